// Round 13
// baseline (785.566 us; speedup 1.0000x reference)
//
#include <hip/hip_runtime.h>
#include <math.h>

namespace {
constexpr int B_N  = 32;
constexpr int SEQ  = 1024;
constexpr int AG   = 256;
constexpr int D    = 256;
constexpr int NH   = 8;
constexpr float SCALE = 0.0625f;
constexpr float EPS   = 1e-12f;

// workspace byte offsets (total ~88 MB)
constexpr size_t HHI_OFF  = 0;          // ushort(bf16) B*SEQ*D = 16 MB
constexpr size_t HLO_OFF  = 16777216;   // ushort(bf16) B*SEQ*D = 16 MB
constexpr size_t HT_OFF   = 33554432;   // ushort(bf16) B*D*SEQ = 16 MB
constexpr size_t MTHI_OFF = 50331648;   // ushort NH*D*D = 1 MB
constexpr size_t MTLO_OFF = 51380224;   // ushort NH*D*D = 1 MB
constexpr size_t MB_OFF   = 52428800;   // u32 B*AG*SEQ/32 = 1 MB
constexpr size_t WVT_OFF  = 53477376;   // ushort NH*D*D = 1 MB
constexpr size_t Z16_OFF  = 54525952;   // ushort B*NH*AG*D = 33.5 MB
}

typedef __attribute__((ext_vector_type(8))) short short8;
typedef __attribute__((ext_vector_type(4))) float floatx4;
#define MFMA_BF(A,B,C) __builtin_amdgcn_mfma_f32_16x16x32_bf16(A,B,C,0,0,0)

__device__ __forceinline__ unsigned short bf16_rtne(float f) {
    unsigned u = __float_as_uint(f);
    u += 0x7fffu + ((u >> 16) & 1u);
    return (unsigned short)(u >> 16);
}
__device__ __forceinline__ float bf16_tof(unsigned short h) {
    return __uint_as_float(((unsigned)h) << 16);
}
// async global->LDS DMA, 16 B/lane; LDS dst = wave-uniform base + lane*16
__device__ __forceinline__ void async16(void* lds, const void* g) {
    __builtin_amdgcn_global_load_lds(
        (const __attribute__((address_space(1))) unsigned int*)g,
        (__attribute__((address_space(3))) unsigned int*)lds,
        16, 0, 0);
}

// ---------------------------------------------------------------------------
// enc_prep v17: enc_mfma (v<2048) merged with prep_fused (2048..3327).
// ---------------------------------------------------------------------------
__global__ __launch_bounds__(256) void enc_prep(
    const float* __restrict__ x, const float* __restrict__ W_enc,
    const float* __restrict__ b_enc,
    ushort* __restrict__ h_hi, ushort* __restrict__ h_lo,
    ushort* __restrict__ hT,
    const float* __restrict__ m, unsigned* __restrict__ mb,
    const float* __restrict__ WV, ushort* __restrict__ WVt,
    const float* __restrict__ WQ, const float* __restrict__ WK,
    ushort* __restrict__ Mt_hi, ushort* __restrict__ Mt_lo)
{
    __shared__ __align__(16) char slds[38912];
    const int t = threadIdx.x;
    const int v = blockIdx.x;

    if (v < 2048) {
        // ---- encoder: h = lrelu(x)@W_enc^T + b (split-bf16 x3 MFMA) + hT
        ushort (*Ah)[40] = (ushort(*)[40])(slds);            // 5120 B
        ushort (*Al)[40] = (ushort(*)[40])(slds + 5120);
        ushort (*Bh)[40] = (ushort(*)[40])(slds + 10240);
        ushort (*Bl)[40] = (ushort(*)[40])(slds + 15360);
        ushort (*Th)[72] = (ushort(*)[72])(slds + 20480);    // 9216 B
        ushort (*Tl)[72] = (ushort(*)[72])(slds + 29696);

        const int wv   = t >> 6;
        const int lane = t & 63;
        const int l15  = lane & 15;
        const int quad = lane >> 4;
        const int col0 = (v & 3) * 64;
        const int vy   = v >> 2;
        const int row0 = vy * 64;

        floatx4 acc[4];
#pragma unroll
        for (int i = 0; i < 4; ++i) acc[i] = (floatx4){0.f, 0.f, 0.f, 0.f};

        for (int k0 = 0; k0 < 256; k0 += 32) {
            __syncthreads();
            {
                const int r = t >> 2, s = (t & 3) * 8;
                float f[8];
                *(float4*)&f[0] = *(const float4*)(x + (size_t)(row0 + r) * 256 + k0 + s);
                *(float4*)&f[4] = *(const float4*)(x + (size_t)(row0 + r) * 256 + k0 + s + 4);
                short8 hi8, lo8;
#pragma unroll
                for (int e = 0; e < 8; ++e) {
                    float vv = f[e] > 0.f ? f[e] : 0.01f * f[e];
                    unsigned short hb = bf16_rtne(vv);
                    hi8[e] = (short)hb;
                    lo8[e] = (short)bf16_rtne(vv - bf16_tof(hb));
                }
                *(short8*)&Ah[r][s] = hi8;
                *(short8*)&Al[r][s] = lo8;
                *(float4*)&f[0] = *(const float4*)(W_enc + (size_t)(col0 + r) * 256 + k0 + s);
                *(float4*)&f[4] = *(const float4*)(W_enc + (size_t)(col0 + r) * 256 + k0 + s + 4);
#pragma unroll
                for (int e = 0; e < 8; ++e) {
                    unsigned short hb = bf16_rtne(f[e]);
                    hi8[e] = (short)hb;
                    lo8[e] = (short)bf16_rtne(f[e] - bf16_tof(hb));
                }
                *(short8*)&Bh[r][s] = hi8;
                *(short8*)&Bl[r][s] = lo8;
            }
            __syncthreads();

            short8 Af  = *(const short8*)&Ah[wv * 16 + l15][quad * 8];
            short8 Afl = *(const short8*)&Al[wv * 16 + l15][quad * 8];
#pragma unroll
            for (int et = 0; et < 4; ++et) {
                short8 Bf  = *(const short8*)&Bh[et * 16 + l15][quad * 8];
                short8 Bfl = *(const short8*)&Bl[et * 16 + l15][quad * 8];
                acc[et] = MFMA_BF(Af,  Bf,  acc[et]);
                acc[et] = MFMA_BF(Afl, Bf,  acc[et]);
                acc[et] = MFMA_BF(Af,  Bfl, acc[et]);
            }
        }

        __syncthreads();
#pragma unroll
        for (int et = 0; et < 4; ++et) {
            const int col = et * 16 + l15;
            const float bb = b_enc[col0 + col];
#pragma unroll
            for (int r = 0; r < 4; ++r) {
                const int row = wv * 16 + quad * 4 + r;
                const float vv = acc[et][r] + bb;
                const unsigned short hb = bf16_rtne(vv);
                Th[row][col] = hb;
                Tl[row][col] = bf16_rtne(vv - bf16_tof(hb));
            }
        }
        __syncthreads();
        {
            const int r = t >> 2, c0 = (t & 3) * 16;
            ushort* dh = h_hi + (size_t)(row0 + r) * 256 + col0 + c0;
            ushort* dl = h_lo + (size_t)(row0 + r) * 256 + col0 + c0;
            *(short8*)dh       = *(const short8*)&Th[r][c0];
            *(short8*)(dh + 8) = *(const short8*)&Th[r][c0 + 8];
            *(short8*)dl       = *(const short8*)&Tl[r][c0];
            *(short8*)(dl + 8) = *(const short8*)&Tl[r][c0 + 8];
        }
        {
            const int bq = vy >> 4;
            const int n0 = (vy & 15) * 64;
            const int dd = t >> 2, seg = (t & 3) * 16;
            ushort tmp[16];
#pragma unroll
            for (int j = 0; j < 16; ++j) tmp[j] = Th[seg + j][dd];
            ushort* dst = hT + ((size_t)(bq * 256 + col0 + dd)) * 1024 + n0 + seg;
            *(short8*)dst       = *(short8*)&tmp[0];
            *(short8*)(dst + 8) = *(short8*)&tmp[8];
        }
    } else if (v < 3072) {
        // ---- maskbits
        const int idx = (v - 2048) * 256 + t;
        const float4* src = (const float4*)(m + (size_t)idx * 32);
        unsigned wbits = 0;
#pragma unroll
        for (int i = 0; i < 8; ++i) {
            float4 vv = src[i];
            wbits |= (vv.x > 0.5f ? 1u : 0u) << (i * 4 + 0);
            wbits |= (vv.y > 0.5f ? 1u : 0u) << (i * 4 + 1);
            wbits |= (vv.z > 0.5f ? 1u : 0u) << (i * 4 + 2);
            wbits |= (vv.w > 0.5f ? 1u : 0u) << (i * 4 + 3);
        }
        mb[idx] = wbits;
    } else if (v < 3200) {
        // ---- wvt: WVt[h][e][d] = bf16(WV[h][d][e]); pitch 68 f32
        float (*T)[68] = (float(*)[68])slds;     // 17408 B
        const int v2 = v - 3072;
        const int d0 = (v2 & 3) * 64, e0 = ((v2 >> 2) & 3) * 64, h = v2 >> 4;
        {
            const int r = t >> 2, c = (t & 3) * 16;
            const float* src = WV + ((size_t)(h * 256 + d0 + r)) * 256 + e0 + c;
#pragma unroll
            for (int j = 0; j < 4; ++j)
                *(float4*)&T[r][c + j * 4] = *(const float4*)(src + j * 4);
        }
        __syncthreads();
        {
            const int ee = t >> 2, seg = (t & 3) * 16;
            ushort tmp[16];
#pragma unroll
            for (int j = 0; j < 16; ++j) tmp[j] = bf16_rtne(T[seg + j][ee]);
            ushort* dst = WVt + ((size_t)(h * 256 + e0 + ee)) * 256 + d0 + seg;
            *(short8*)dst       = *(short8*)&tmp[0];
            *(short8*)(dst + 8) = *(short8*)&tmp[8];
        }
    } else {
        // ---- mprep: Mt_h[d'][d] = (WQ_h @ WK_h^T)[d][d'] -> bf16 hi/lo
        float (*AsT)[68] = (float(*)[68])slds;           // 8704 B
        float (*BsT)[68] = (float(*)[68])(slds + 8704);  // 8704 B
        const int v3 = v - 3200;
        const int tx = t & 15, ty = t >> 4;
        const int col0 = (v3 & 3) * 64;
        const int row0 = ((v3 >> 2) & 3) * 64;
        const int hz   = v3 >> 4;
        const float* A  = WK + (size_t)hz * 256 * 256;
        const float* Bm = WQ + (size_t)hz * 256 * 256;
        ushort* Chi = Mt_hi + (size_t)hz * 256 * 256;
        ushort* Clo = Mt_lo + (size_t)hz * 256 * 256;

        float acc[4][4];
#pragma unroll
        for (int r = 0; r < 4; ++r)
#pragma unroll
            for (int c = 0; c < 4; ++c) acc[r][c] = 0.f;

        for (int k0 = 0; k0 < 256; k0 += 32) {
            __syncthreads();
#pragma unroll
            for (int ss = 0; ss < 2; ++ss) {
                int flat = t + 256 * ss;
                int rr = flat >> 3, k4 = flat & 7;
                float4 vv = *(const float4*)(A + (size_t)(row0 + rr) * 256 + k0 + k4 * 4);
                AsT[k4*4+0][rr] = vv.x; AsT[k4*4+1][rr] = vv.y;
                AsT[k4*4+2][rr] = vv.z; AsT[k4*4+3][rr] = vv.w;
                float4 wv = *(const float4*)(Bm + (size_t)(col0 + rr) * 256 + k0 + k4 * 4);
                BsT[k4*4+0][rr] = wv.x; BsT[k4*4+1][rr] = wv.y;
                BsT[k4*4+2][rr] = wv.z; BsT[k4*4+3][rr] = wv.w;
            }
            __syncthreads();
#pragma unroll 8
            for (int kk = 0; kk < 32; ++kk) {
                float4 a4 = *(const float4*)&AsT[kk][ty * 4];
                float4 b4 = *(const float4*)&BsT[kk][tx * 4];
                const float ar[4] = {a4.x, a4.y, a4.z, a4.w};
                const float bc[4] = {b4.x, b4.y, b4.z, b4.w};
#pragma unroll
                for (int r = 0; r < 4; ++r)
#pragma unroll
                    for (int c = 0; c < 4; ++c)
                        acc[r][c] = fmaf(ar[r], bc[c], acc[r][c]);
            }
        }
#pragma unroll
        for (int r = 0; r < 4; ++r) {
            const int row = row0 + ty * 4 + r;
            ushort hi4[4], lo4[4];
#pragma unroll
            for (int c = 0; c < 4; ++c) {
                float vv = acc[r][c];
                hi4[c] = bf16_rtne(vv);
                lo4[c] = bf16_rtne(vv - bf16_tof(hi4[c]));
            }
            *(ushort4*)(Chi + (size_t)row * 256 + col0 + tx * 4) =
                make_ushort4(hi4[0], hi4[1], hi4[2], hi4[3]);
            *(ushort4*)(Clo + (size_t)row * 256 + col0 + tx * 4) =
                make_ushort4(lo4[0], lo4[1], lo4[2], lo4[3]);
        }
    }
}

// ---------------------------------------------------------------------------
// Attention v19: hTS LDS staging ELIMINATED -- PV B-frags prefetched from
// global hT into registers with issue-early/consume-late (T14): dt 0-7
// issued at loop head (covered by the whole S phase), dt 8-15 issued after
// S (covered by softmax). v14 proved these exact loads fail when issued
// inside the PV loop (no slack at 2 waves/SIMD); prefetching provides ~5k
// cycles of cover vs ~200cy L2 latency. Removes 1/3 of staging DMA and the
// 16 swizzled PV LDS reads/lane/iter (~31% of LDS traffic). Same values,
// same accumulation order as v10/v17 -> identical numerics.
// Register budget: +32 VGPR in flight, ~236 unified <= 256 bucket (spill
// tripwire: WRITE_SIZE must stay 32768). LDS 86016 B.
// ---------------------------------------------------------------------------
__global__ __launch_bounds__(512, 2) void attn_mfma(
    const ushort* __restrict__ h_hi, const ushort* __restrict__ h_lo,
    const ushort* __restrict__ hT,   const ushort* __restrict__ Mt_hi,
    const ushort* __restrict__ Mt_lo, const unsigned* __restrict__ mbits,
    ushort* __restrict__ zout)
{
    // buf k at k*32768: hS_hi 16384 | hS_lo 16384 ;
    // pP at 65536 (10240) ; pE at 75776 (10240)  -> 86016 B total
    __shared__ __align__(16) char lds[86016];
    ushort* pP = (ushort*)(lds + 65536);   // [128][40] bf16 masked p
    ushort* pE = (ushort*)(lds + 75776);   // [128][40] bf16 unmasked e

    const int t    = threadIdx.x;
    const int wv   = t >> 6;          // 0..7
    const int lane = t & 63;
    const int l15  = lane & 15;
    const int quad = lane >> 4;
    const int f    = blockIdx.x;      // 512 blocks
    const int b    = (f & 7) + 8 * (f >> 7);
    const int mid  = (f >> 3) & 15;
    const int hh   = (mid >> 2) * 2 + (wv >> 2);   // head per wave
    const int a0   = (mid & 3) * 64;
    const int aw   = a0 + (wv & 3) * 16;           // a-subtile per wave

    const ushort* hbh = h_hi + (size_t)b * SEQ * D;
    const ushort* hbl = h_lo + (size_t)b * SEQ * D;
    const ushort* hTb = hT   + (size_t)b * D * SEQ;

    // ---- Phase 0: Q' = ha @ Mt^T (split-bf16 x3), C-layout fp32 tiles
    floatx4 qac[16];
#pragma unroll
    for (int i = 0; i < 16; ++i) qac[i] = (floatx4){0.f, 0.f, 0.f, 0.f};

    for (int kc = 0; kc < 4; ++kc) {
        short8 Ah[2], Al[2];
#pragma unroll
        for (int kt = 0; kt < 2; ++kt) {
            const size_t ao = ((size_t)b * SEQ + aw + l15) * D +
                              kc * 64 + kt * 32 + quad * 8;
            Ah[kt] = *(const short8*)(h_hi + ao);
            Al[kt] = *(const short8*)(h_lo + ao);
        }
#pragma unroll
        for (int nt2 = 0; nt2 < 16; ++nt2) {
#pragma unroll
            for (int kt = 0; kt < 2; ++kt) {
                const size_t mo = ((size_t)hh * D + nt2 * 16 + l15) * D +
                                  kc * 64 + kt * 32 + quad * 8;
                short8 Bh = *(const short8*)(Mt_hi + mo);
                short8 Bl = *(const short8*)(Mt_lo + mo);
                qac[nt2] = MFMA_BF(Ah[kt], Bh, qac[nt2]);
                qac[nt2] = MFMA_BF(Al[kt], Bh, qac[nt2]);
                qac[nt2] = MFMA_BF(Ah[kt], Bl, qac[nt2]);
            }
        }
    }

    // repack Q' C-layout -> bf16 hi/lo A-frags via fp32 scratch at lds base
    // (wave-private rows, pitch 68 f32; 34.8 KB < 64 KB of buf0+buf1)
    short8 Qhi[8], Qlo[8];
    {
        float* qscr = (float*)lds;
        for (int c = 0; c < 4; ++c) {
#pragma unroll
            for (int j = 0; j < 4; ++j)
#pragma unroll
                for (int r = 0; r < 4; ++r)
                    qscr[(wv * 16 + quad * 4 + r) * 68 + j * 16 + l15] = qac[c * 4 + j][r];
#pragma unroll
            for (int kt = 0; kt < 2; ++kt) {
                const float* pr = &qscr[(wv * 16 + l15) * 68 + kt * 32 + quad * 8];
                float ftmp[8];
                *(float4*)&ftmp[0] = *(const float4*)pr;
                *(float4*)&ftmp[4] = *(const float4*)(pr + 4);
                short8 hi, lo;
#pragma unroll
                for (int e = 0; e < 8; ++e) {
                    unsigned short hb = bf16_rtne(ftmp[e]);
                    hi[e] = (short)hb;
                    lo[e] = (short)bf16_rtne(ftmp[e] - bf16_tof(hb));
                }
                Qhi[c * 2 + kt] = hi;
                Qlo[c * 2 + kt] = lo;
            }
        }
    }
    __syncthreads();   // all waves done with Q' scratch before DMA into buf0

    // ---- DMA issue helper (tile n0 -> buf; hS hi+lo only, 4 async16/thr)
    auto issue_tile = [&](char* buf, int n0) {
        ushort* dh = (ushort*)buf;
        ushort* dl = (ushort*)(buf + 16384);
#pragma unroll
        for (int i = 0; i < 2; ++i) {
            const int slot = wv * 128 + i * 64 + lane;
            const int row  = slot >> 5;
            const int p    = slot & 31;
            const int c    = p ^ (row & 7);
            const size_t go = (size_t)(n0 + row) * 256 + c * 8;
            const size_t lo_ = (size_t)(wv * 128 + i * 64) * 8;
            async16(dh + lo_, hbh + go);
            async16(dl + lo_, hbl + go);
        }
    };

    // prologue: tiles 0 and 1 in flight, then drain once
    issue_tile(lds,         0);
    issue_tile(lds + 32768, 32);
    __syncthreads();

    // ---- Phase 1: pipelined flash loop over 32 n-tiles of 32 rows
    floatx4 zac[16];
#pragma unroll
    for (int i = 0; i < 16; ++i) zac[i] = (floatx4){0.f, 0.f, 0.f, 0.f};
    floatx4 zacZ = (floatx4){0.f, 0.f, 0.f, 0.f};   // Zm row-sums (MFMA ones)
    floatx4 zacE = (floatx4){0.f, 0.f, 0.f, 0.f};   // Za row-sums (MFMA ones)
    float mx[4] = {-INFINITY, -INFINITY, -INFINITY, -INFINITY};

    short8 onesf;
#pragma unroll
    for (int e = 0; e < 8; ++e) onesf[e] = (short)0x3F80;   // bf16 1.0

    const unsigned* mbr = mbits + ((size_t)b * AG + aw + quad * 4) * (SEQ / 32);
    const ushort*   hTl = hTb + (size_t)l15 * 1024 + quad * 8;

    for (int nt = 0; nt < 32; ++nt) {
        const int n0 = nt * 32;
        char* cur = lds + (size_t)(nt & 1) * 32768;
        ushort* hS_hi = (ushort*)cur;
        ushort* hS_lo = (ushort*)(cur + 16384);

        // T14 prefetch, first half: PV B-frags dt 0..7 (global hT,
        // L2-resident; latency covered by the whole S phase below)
        short8 Bv0[8];
#pragma unroll
        for (int dt = 0; dt < 8; ++dt)
            Bv0[dt] = *(const short8*)(hTl + (size_t)dt * 16384 + n0);

        // S = Q' @ h^T  (split-bf16 x3; swizzled b128 reads; 4 acc chains)
        floatx4 sacH[2], sacL[2];
        sacH[0] = (floatx4){0.f, 0.f, 0.f, 0.f};
        sacH[1] = (floatx4){0.f, 0.f, 0.f, 0.f};
        sacL[0] = (floatx4){0.f, 0.f, 0.f, 0.f};
        sacL[1] = (floatx4){0.f, 0.f, 0.f, 0.f};
        __builtin_amdgcn_s_setprio(1);
#pragma unroll
        for (int ks = 0; ks < 8; ++ks) {
            const int cg = ks * 4 + quad;
#pragma unroll
            for (int ntile = 0; ntile < 2; ++ntile) {
                const int row = ntile * 16 + l15;
                const int off = row * 256 + (cg ^ (row & 7)) * 8;
                short8 Bh = *(const short8*)&hS_hi[off];
                short8 Bl = *(const short8*)&hS_lo[off];
                sacH[ntile] = MFMA_BF(Qhi[ks], Bh, sacH[ntile]);
                sacL[ntile] = MFMA_BF(Qlo[ks], Bh, sacL[ntile]);
                sacL[ntile] = MFMA_BF(Qhi[ks], Bl, sacL[ntile]);
            }
        }
        __builtin_amdgcn_s_setprio(0);

        // T14 prefetch, second half: dt 8..15 (covered by softmax below)
        short8 Bv1[8];
#pragma unroll
        for (int dt = 0; dt < 8; ++dt)
            Bv1[dt] = *(const short8*)(hTl + (size_t)(dt + 8) * 16384 + n0);

        // logits for this wave's 16x32 tile (4 rows per lane)
        float l0[4], l1[4];
#pragma unroll
        for (int r = 0; r < 4; ++r) {
            l0[r] = (sacH[0][r] + sacL[0][r]) * SCALE;
            l1[r] = (sacH[1][r] + sacL[1][r]) * SCALE;
        }

        // per-row tile max: 4-deep 16-lane butterfly, 4 independent chains
        float mt[4];
#pragma unroll
        for (int r = 0; r < 4; ++r) mt[r] = fmaxf(l0[r], l1[r]);
#pragma unroll
        for (int off = 1; off < 16; off <<= 1) {
#pragma unroll
            for (int r = 0; r < 4; ++r)
                mt[r] = fmaxf(mt[r], __shfl_xor(mt[r], off));
        }

        // deferred rescale (rare, wave-uniform branch)
        const bool need = (mt[0] > mx[0] + 8.0f) || (mt[1] > mx[1] + 8.0f) ||
                          (mt[2] > mx[2] + 8.0f) || (mt[3] > mx[3] + 8.0f);
        if (__any(need)) {
            float alr[4];
#pragma unroll
            for (int r = 0; r < 4; ++r) {
                const float mxn = fmaxf(mx[r], mt[r]);
                alr[r] = __expf(mx[r] - mxn);
                mx[r] = mxn;
            }
#pragma unroll
            for (int dt = 0; dt < 16; ++dt) {
                zac[dt][0] *= alr[0]; zac[dt][1] *= alr[1];
                zac[dt][2] *= alr[2]; zac[dt][3] *= alr[3];
            }
            zacZ[0] *= alr[0]; zacZ[1] *= alr[1];
            zacZ[2] *= alr[2]; zacZ[3] *= alr[3];
            zacE[0] *= alr[0]; zacE[1] *= alr[1];
            zacE[2] *= alr[2]; zacE[3] *= alr[3];
        }

        // masked p and unmasked e -> bf16 LDS frags (no lane reductions)
#pragma unroll
        for (int r = 0; r < 4; ++r) {
            const unsigned w0 = mbr[r * (SEQ / 32) + nt];
            const float e0 = __expf(l0[r] - mx[r]);
            const float e1 = __expf(l1[r] - mx[r]);
            const float p0 = ((w0 >> l15) & 1u)        ? e0 : 0.f;
            const float p1 = ((w0 >> (16 + l15)) & 1u) ? e1 : 0.f;
            const int row = wv * 16 + quad * 4 + r;
            pP[row * 40 + l15]      = bf16_rtne(p0);
            pP[row * 40 + 16 + l15] = bf16_rtne(p1);
            pE[row * 40 + l15]      = bf16_rtne(e0);
            pE[row * 40 + 16 + l15] = bf16_rtne(e1);
        }

        // row-sums via MFMA with immediate ones B-frag: Zm (masked), Za (raw)
        short8 Pf = *(const short8*)&pP[(wv * 16 + l15) * 40 + quad * 8];
        short8 Ef = *(const short8*)&pE[(wv * 16 + l15) * 40 + quad * 8];
        zacZ = MFMA_BF(Pf, onesf, zacZ);
        zacE = MFMA_BF(Ef, onesf, zacE);

        // z += P @ h : P A-frag (wave-private pP), B-frags from registers
        __builtin_amdgcn_s_setprio(1);
#pragma unroll
        for (int dt = 0; dt < 8; ++dt)
            zac[dt] = MFMA_BF(Pf, Bv0[dt], zac[dt]);
#pragma unroll
        for (int dt = 0; dt < 8; ++dt)
            zac[dt + 8] = MFMA_BF(Pf, Bv1[dt], zac[dt + 8]);
        __builtin_amdgcn_s_setprio(0);

        // barrier: everyone done reading cur; DMA(nt+1) — issued one full
        // iteration ago — drains here with a tile's worth of slack.
        __syncthreads();
        if (nt + 2 < 32) issue_tile(cur, (nt + 2) * 32);
    }

    // epilogue: z_bf16 = z / (Zm + EPS*Za)
#pragma unroll
    for (int r = 0; r < 4; ++r) {
        const int a = aw + quad * 4 + r;
        const float inv = 1.0f / (zacZ[r] + EPS * zacE[r]);
        ushort* zr = zout + (((size_t)b * NH + hh) * AG + a) * D;
#pragma unroll
        for (int dt = 0; dt < 16; ++dt)
            zr[dt * 16 + l15] = bf16_rtne(zac[dt][r] * inv);
    }
}

// ---------------------------------------------------------------------------
// out v18: 64x64 tile + XCD swizzle + z16 A-operand LDS-staged via DMA
// double-buffer (proven +9 us vs global-operand MFMA at 2 waves/SIMD).
// ---------------------------------------------------------------------------
__global__ __launch_bounds__(256) void out_mfma(
    const ushort* __restrict__ z16, const ushort* __restrict__ WVt,
    float* __restrict__ out)
{
    __shared__ __align__(16) char olds[65536];
    const int t    = threadIdx.x;
    const int wv   = t >> 6;
    const int lane = t & 63;
    const int l15  = lane & 15;
    const int quad = lane >> 4;
    const int f    = blockIdx.x;               // 512 blocks
    const int b    = (f & 7) + 8 * (f >> 7);   // same-b -> same XCD
    const int mid  = (f >> 3) & 15;
    const int e0   = (mid & 3) * 64;
    const int a0   = (mid >> 2) * 64;
    const int aw   = a0 + wv * 16;

    const ushort* zb = z16 + (size_t)b * NH * AG * D;

    // DMA head-hh tile (rows a0..a0+63, all 256 d) into buf, XOR-swizzled:
    // LDS slot (row, p) holds global col-group c = p ^ (row & 7).
    auto stage = [&](char* buf, int hh) {
        ushort* dst = (ushort*)buf;
        const ushort* src = zb + (size_t)hh * AG * D;
#pragma unroll
        for (int i = 0; i < 8; ++i) {
            const int slot = i * 256 + t;        // 0..2047
            const int row  = slot >> 5;          // 0..63
            const int p    = slot & 31;
            const int c    = p ^ (row & 7);
            async16(dst + (size_t)slot * 8,
                    src + (size_t)(a0 + row) * D + c * 8);
        }
    };

    floatx4 acc[4];
#pragma unroll
    for (int i = 0; i < 4; ++i) acc[i] = (floatx4){0.f, 0.f, 0.f, 0.f};

    stage(olds, 0);
    __syncthreads();

    for (int hh = 0; hh < 8; ++hh) {
        char* cur = olds + (size_t)(hh & 1) * 32768;
        if (hh + 1 < 8) stage(olds + (size_t)((hh + 1) & 1) * 32768, hh + 1);

        ushort* zt = (ushort*)cur;
        const int lrow = wv * 16 + l15;          // LDS row (local a)
#pragma unroll
        for (int ci = 0; ci < 8; ++ci) {
            const int d0 = ci * 32;
            const int g  = ci * 4 + quad;        // global col-group 0..31
            short8 Af = *(const short8*)&zt[(size_t)lrow * 256 +
                                            (g ^ (lrow & 7)) * 8];
#pragma unroll
            for (int et = 0; et < 4; ++et) {
                short8 Bf = *(const short8*)(WVt +
                    ((size_t)hh * D + e0 + et * 16 + l15) * D + d0 + quad * 8);
                acc[et] = MFMA_BF(Af, Bf, acc[et]);
            }
        }
        // implicit vmcnt(0) completes DMA(hh+1); all waves done reading cur
        __syncthreads();
    }

#pragma unroll
    for (int et = 0; et < 4; ++et)
#pragma unroll
        for (int r = 0; r < 4; ++r)
            out[((size_t)b * AG + aw + quad * 4 + r) * D + e0 + et * 16 + l15] =
                acc[et][r] * 0.125f;
}

// ---------------------------------------------------------------------------
extern "C" void kernel_launch(void* const* d_in, const int* in_sizes, int n_in,
                              void* d_out, int out_size, void* d_ws, size_t ws_size,
                              hipStream_t stream)
{
    (void)in_sizes; (void)n_in; (void)out_size; (void)ws_size;
    const float* x     = (const float*)d_in[0];
    const float* m     = (const float*)d_in[1];
    const float* W_enc = (const float*)d_in[2];
    const float* b_enc = (const float*)d_in[3];
    const float* WQ    = (const float*)d_in[4];
    const float* WK    = (const float*)d_in[5];
    const float* WV    = (const float*)d_in[6];
    float* out = (float*)d_out;
    char* ws = (char*)d_ws;

    ushort*   h_hi  = (ushort*)(ws + HHI_OFF);
    ushort*   h_lo  = (ushort*)(ws + HLO_OFF);
    ushort*   hT    = (ushort*)(ws + HT_OFF);
    ushort*   Mt_hi = (ushort*)(ws + MTHI_OFF);
    ushort*   Mt_lo = (ushort*)(ws + MTLO_OFF);
    unsigned* mbits = (unsigned*)(ws + MB_OFF);
    ushort*   WVt   = (ushort*)(ws + WVT_OFF);
    ushort*   z16   = (ushort*)(ws + Z16_OFF);

    enc_prep<<<dim3(3328, 1, 1), dim3(256), 0, stream>>>(
        x, W_enc, b_enc, h_hi, h_lo, hT,
        m, mbits, WV, WVt, WQ, WK, Mt_hi, Mt_lo);
    attn_mfma<<<dim3(512, 1, 1), dim3(512), 0, stream>>>(
        h_hi, h_lo, hT, Mt_hi, Mt_lo, mbits, z16);
    out_mfma<<<dim3(512, 1, 1), dim3(256), 0, stream>>>(z16, WVt, out);
}

// Round 14
// 512.927 us; speedup vs baseline: 1.5315x; 1.5315x over previous
//
#include <hip/hip_runtime.h>
#include <math.h>

namespace {
constexpr int B_N  = 32;
constexpr int SEQ  = 1024;
constexpr int AG   = 256;
constexpr int D    = 256;
constexpr int NH   = 8;
constexpr float SCALE = 0.0625f;
constexpr float EPS   = 1e-12f;

// workspace byte offsets (total ~88 MB)
constexpr size_t HHI_OFF  = 0;          // ushort(bf16) B*SEQ*D = 16 MB
constexpr size_t HLO_OFF  = 16777216;   // ushort(bf16) B*SEQ*D = 16 MB
constexpr size_t HT_OFF   = 33554432;   // ushort(bf16) B*D*SEQ = 16 MB
constexpr size_t MTHI_OFF = 50331648;   // ushort NH*D*D = 1 MB
constexpr size_t MTLO_OFF = 51380224;   // ushort NH*D*D = 1 MB
constexpr size_t MB_OFF   = 52428800;   // u32 B*AG*SEQ/32 = 1 MB
constexpr size_t WVT_OFF  = 53477376;   // ushort NH*D*D = 1 MB
constexpr size_t Z16_OFF  = 54525952;   // ushort B*NH*AG*D = 33.5 MB
}

typedef __attribute__((ext_vector_type(8))) short short8;
typedef __attribute__((ext_vector_type(4))) float floatx4;
#define MFMA_BF(A,B,C) __builtin_amdgcn_mfma_f32_16x16x32_bf16(A,B,C,0,0,0)

__device__ __forceinline__ unsigned short bf16_rtne(float f) {
    unsigned u = __float_as_uint(f);
    u += 0x7fffu + ((u >> 16) & 1u);
    return (unsigned short)(u >> 16);
}
__device__ __forceinline__ float bf16_tof(unsigned short h) {
    return __uint_as_float(((unsigned)h) << 16);
}
// async global->LDS DMA, 16 B/lane; LDS dst = wave-uniform base + lane*16
__device__ __forceinline__ void async16(void* lds, const void* g) {
    __builtin_amdgcn_global_load_lds(
        (const __attribute__((address_space(1))) unsigned int*)g,
        (__attribute__((address_space(3))) unsigned int*)lds,
        16, 0, 0);
}

// ---------------------------------------------------------------------------
// enc_prep v17: enc_mfma (v<2048) merged with prep_fused (2048..3327).
// ---------------------------------------------------------------------------
__global__ __launch_bounds__(256) void enc_prep(
    const float* __restrict__ x, const float* __restrict__ W_enc,
    const float* __restrict__ b_enc,
    ushort* __restrict__ h_hi, ushort* __restrict__ h_lo,
    ushort* __restrict__ hT,
    const float* __restrict__ m, unsigned* __restrict__ mb,
    const float* __restrict__ WV, ushort* __restrict__ WVt,
    const float* __restrict__ WQ, const float* __restrict__ WK,
    ushort* __restrict__ Mt_hi, ushort* __restrict__ Mt_lo)
{
    __shared__ __align__(16) char slds[38912];
    const int t = threadIdx.x;
    const int v = blockIdx.x;

    if (v < 2048) {
        // ---- encoder: h = lrelu(x)@W_enc^T + b (split-bf16 x3 MFMA) + hT
        ushort (*Ah)[40] = (ushort(*)[40])(slds);            // 5120 B
        ushort (*Al)[40] = (ushort(*)[40])(slds + 5120);
        ushort (*Bh)[40] = (ushort(*)[40])(slds + 10240);
        ushort (*Bl)[40] = (ushort(*)[40])(slds + 15360);
        ushort (*Th)[72] = (ushort(*)[72])(slds + 20480);    // 9216 B
        ushort (*Tl)[72] = (ushort(*)[72])(slds + 29696);

        const int wv   = t >> 6;
        const int lane = t & 63;
        const int l15  = lane & 15;
        const int quad = lane >> 4;
        const int col0 = (v & 3) * 64;
        const int vy   = v >> 2;
        const int row0 = vy * 64;

        floatx4 acc[4];
#pragma unroll
        for (int i = 0; i < 4; ++i) acc[i] = (floatx4){0.f, 0.f, 0.f, 0.f};

        for (int k0 = 0; k0 < 256; k0 += 32) {
            __syncthreads();
            {
                const int r = t >> 2, s = (t & 3) * 8;
                float f[8];
                *(float4*)&f[0] = *(const float4*)(x + (size_t)(row0 + r) * 256 + k0 + s);
                *(float4*)&f[4] = *(const float4*)(x + (size_t)(row0 + r) * 256 + k0 + s + 4);
                short8 hi8, lo8;
#pragma unroll
                for (int e = 0; e < 8; ++e) {
                    float vv = f[e] > 0.f ? f[e] : 0.01f * f[e];
                    unsigned short hb = bf16_rtne(vv);
                    hi8[e] = (short)hb;
                    lo8[e] = (short)bf16_rtne(vv - bf16_tof(hb));
                }
                *(short8*)&Ah[r][s] = hi8;
                *(short8*)&Al[r][s] = lo8;
                *(float4*)&f[0] = *(const float4*)(W_enc + (size_t)(col0 + r) * 256 + k0 + s);
                *(float4*)&f[4] = *(const float4*)(W_enc + (size_t)(col0 + r) * 256 + k0 + s + 4);
#pragma unroll
                for (int e = 0; e < 8; ++e) {
                    unsigned short hb = bf16_rtne(f[e]);
                    hi8[e] = (short)hb;
                    lo8[e] = (short)bf16_rtne(f[e] - bf16_tof(hb));
                }
                *(short8*)&Bh[r][s] = hi8;
                *(short8*)&Bl[r][s] = lo8;
            }
            __syncthreads();

            short8 Af  = *(const short8*)&Ah[wv * 16 + l15][quad * 8];
            short8 Afl = *(const short8*)&Al[wv * 16 + l15][quad * 8];
#pragma unroll
            for (int et = 0; et < 4; ++et) {
                short8 Bf  = *(const short8*)&Bh[et * 16 + l15][quad * 8];
                short8 Bfl = *(const short8*)&Bl[et * 16 + l15][quad * 8];
                acc[et] = MFMA_BF(Af,  Bf,  acc[et]);
                acc[et] = MFMA_BF(Afl, Bf,  acc[et]);
                acc[et] = MFMA_BF(Af,  Bfl, acc[et]);
            }
        }

        __syncthreads();
#pragma unroll
        for (int et = 0; et < 4; ++et) {
            const int col = et * 16 + l15;
            const float bb = b_enc[col0 + col];
#pragma unroll
            for (int r = 0; r < 4; ++r) {
                const int row = wv * 16 + quad * 4 + r;
                const float vv = acc[et][r] + bb;
                const unsigned short hb = bf16_rtne(vv);
                Th[row][col] = hb;
                Tl[row][col] = bf16_rtne(vv - bf16_tof(hb));
            }
        }
        __syncthreads();
        {
            const int r = t >> 2, c0 = (t & 3) * 16;
            ushort* dh = h_hi + (size_t)(row0 + r) * 256 + col0 + c0;
            ushort* dl = h_lo + (size_t)(row0 + r) * 256 + col0 + c0;
            *(short8*)dh       = *(const short8*)&Th[r][c0];
            *(short8*)(dh + 8) = *(const short8*)&Th[r][c0 + 8];
            *(short8*)dl       = *(const short8*)&Tl[r][c0];
            *(short8*)(dl + 8) = *(const short8*)&Tl[r][c0 + 8];
        }
        {
            const int bq = vy >> 4;
            const int n0 = (vy & 15) * 64;
            const int dd = t >> 2, seg = (t & 3) * 16;
            ushort tmp[16];
#pragma unroll
            for (int j = 0; j < 16; ++j) tmp[j] = Th[seg + j][dd];
            ushort* dst = hT + ((size_t)(bq * 256 + col0 + dd)) * 1024 + n0 + seg;
            *(short8*)dst       = *(short8*)&tmp[0];
            *(short8*)(dst + 8) = *(short8*)&tmp[8];
        }
    } else if (v < 3072) {
        // ---- maskbits
        const int idx = (v - 2048) * 256 + t;
        const float4* src = (const float4*)(m + (size_t)idx * 32);
        unsigned wbits = 0;
#pragma unroll
        for (int i = 0; i < 8; ++i) {
            float4 vv = src[i];
            wbits |= (vv.x > 0.5f ? 1u : 0u) << (i * 4 + 0);
            wbits |= (vv.y > 0.5f ? 1u : 0u) << (i * 4 + 1);
            wbits |= (vv.z > 0.5f ? 1u : 0u) << (i * 4 + 2);
            wbits |= (vv.w > 0.5f ? 1u : 0u) << (i * 4 + 3);
        }
        mb[idx] = wbits;
    } else if (v < 3200) {
        // ---- wvt: WVt[h][e][d] = bf16(WV[h][d][e]); pitch 68 f32
        float (*T)[68] = (float(*)[68])slds;     // 17408 B
        const int v2 = v - 3072;
        const int d0 = (v2 & 3) * 64, e0 = ((v2 >> 2) & 3) * 64, h = v2 >> 4;
        {
            const int r = t >> 2, c = (t & 3) * 16;
            const float* src = WV + ((size_t)(h * 256 + d0 + r)) * 256 + e0 + c;
#pragma unroll
            for (int j = 0; j < 4; ++j)
                *(float4*)&T[r][c + j * 4] = *(const float4*)(src + j * 4);
        }
        __syncthreads();
        {
            const int ee = t >> 2, seg = (t & 3) * 16;
            ushort tmp[16];
#pragma unroll
            for (int j = 0; j < 16; ++j) tmp[j] = bf16_rtne(T[seg + j][ee]);
            ushort* dst = WVt + ((size_t)(h * 256 + e0 + ee)) * 256 + d0 + seg;
            *(short8*)dst       = *(short8*)&tmp[0];
            *(short8*)(dst + 8) = *(short8*)&tmp[8];
        }
    } else {
        // ---- mprep: Mt_h[d'][d] = (WQ_h @ WK_h^T)[d][d'] -> bf16 hi/lo
        float (*AsT)[68] = (float(*)[68])slds;           // 8704 B
        float (*BsT)[68] = (float(*)[68])(slds + 8704);  // 8704 B
        const int v3 = v - 3200;
        const int tx = t & 15, ty = t >> 4;
        const int col0 = (v3 & 3) * 64;
        const int row0 = ((v3 >> 2) & 3) * 64;
        const int hz   = v3 >> 4;
        const float* A  = WK + (size_t)hz * 256 * 256;
        const float* Bm = WQ + (size_t)hz * 256 * 256;
        ushort* Chi = Mt_hi + (size_t)hz * 256 * 256;
        ushort* Clo = Mt_lo + (size_t)hz * 256 * 256;

        float acc[4][4];
#pragma unroll
        for (int r = 0; r < 4; ++r)
#pragma unroll
            for (int c = 0; c < 4; ++c) acc[r][c] = 0.f;

        for (int k0 = 0; k0 < 256; k0 += 32) {
            __syncthreads();
#pragma unroll
            for (int ss = 0; ss < 2; ++ss) {
                int flat = t + 256 * ss;
                int rr = flat >> 3, k4 = flat & 7;
                float4 vv = *(const float4*)(A + (size_t)(row0 + rr) * 256 + k0 + k4 * 4);
                AsT[k4*4+0][rr] = vv.x; AsT[k4*4+1][rr] = vv.y;
                AsT[k4*4+2][rr] = vv.z; AsT[k4*4+3][rr] = vv.w;
                float4 wv = *(const float4*)(Bm + (size_t)(col0 + rr) * 256 + k0 + k4 * 4);
                BsT[k4*4+0][rr] = wv.x; BsT[k4*4+1][rr] = wv.y;
                BsT[k4*4+2][rr] = wv.z; BsT[k4*4+3][rr] = wv.w;
            }
            __syncthreads();
#pragma unroll 8
            for (int kk = 0; kk < 32; ++kk) {
                float4 a4 = *(const float4*)&AsT[kk][ty * 4];
                float4 b4 = *(const float4*)&BsT[kk][tx * 4];
                const float ar[4] = {a4.x, a4.y, a4.z, a4.w};
                const float bc[4] = {b4.x, b4.y, b4.z, b4.w};
#pragma unroll
                for (int r = 0; r < 4; ++r)
#pragma unroll
                    for (int c = 0; c < 4; ++c)
                        acc[r][c] = fmaf(ar[r], bc[c], acc[r][c]);
            }
        }
#pragma unroll
        for (int r = 0; r < 4; ++r) {
            const int row = row0 + ty * 4 + r;
            ushort hi4[4], lo4[4];
#pragma unroll
            for (int c = 0; c < 4; ++c) {
                float vv = acc[r][c];
                hi4[c] = bf16_rtne(vv);
                lo4[c] = bf16_rtne(vv - bf16_tof(hi4[c]));
            }
            *(ushort4*)(Chi + (size_t)row * 256 + col0 + tx * 4) =
                make_ushort4(hi4[0], hi4[1], hi4[2], hi4[3]);
            *(ushort4*)(Clo + (size_t)row * 256 + col0 + tx * 4) =
                make_ushort4(lo4[0], lo4[1], lo4[2], lo4[3]);
        }
    }
}

// ---------------------------------------------------------------------------
// Attention (proven 330-332 us): v10 structure + neutral setprio. v19's
// register-prefetched PV spilled (WRITE_SIZE 32768->59392: +64 VGPR of live
// Bv state blew the <=256 bucket) -- the attn working set leaves <~40 VGPR
// headroom; LDS-staged hTS is the right home for PV operands.
// ---------------------------------------------------------------------------
__global__ __launch_bounds__(512, 2) void attn_mfma(
    const ushort* __restrict__ h_hi, const ushort* __restrict__ h_lo,
    const ushort* __restrict__ hT,   const ushort* __restrict__ Mt_hi,
    const ushort* __restrict__ Mt_lo, const unsigned* __restrict__ mbits,
    ushort* __restrict__ zout)
{
    // buf k at k*49152: hS_hi 16384 | hS_lo 16384 | hTS 16384 ;
    // pP at 98304 (10240) ; pE at 108544 (10240)  -> 118784 B total
    __shared__ __align__(16) char lds[118784];
    ushort* pP = (ushort*)(lds + 98304);   // [128][40] bf16 masked p
    ushort* pE = (ushort*)(lds + 108544);  // [128][40] bf16 unmasked e

    const int t    = threadIdx.x;
    const int wv   = t >> 6;          // 0..7
    const int lane = t & 63;
    const int l15  = lane & 15;
    const int quad = lane >> 4;
    const int f    = blockIdx.x;      // 512 blocks
    const int b    = (f & 7) + 8 * (f >> 7);
    const int mid  = (f >> 3) & 15;
    const int hh   = (mid >> 2) * 2 + (wv >> 2);   // head per wave
    const int a0   = (mid & 3) * 64;
    const int aw   = a0 + (wv & 3) * 16;           // a-subtile per wave

    const ushort* hbh = h_hi + (size_t)b * SEQ * D;
    const ushort* hbl = h_lo + (size_t)b * SEQ * D;
    const ushort* hTb = hT   + (size_t)b * D * SEQ;

    // ---- Phase 0: Q' = ha @ Mt^T (split-bf16 x3), C-layout fp32 tiles
    floatx4 qac[16];
#pragma unroll
    for (int i = 0; i < 16; ++i) qac[i] = (floatx4){0.f, 0.f, 0.f, 0.f};

    for (int kc = 0; kc < 4; ++kc) {
        short8 Ah[2], Al[2];
#pragma unroll
        for (int kt = 0; kt < 2; ++kt) {
            const size_t ao = ((size_t)b * SEQ + aw + l15) * D +
                              kc * 64 + kt * 32 + quad * 8;
            Ah[kt] = *(const short8*)(h_hi + ao);
            Al[kt] = *(const short8*)(h_lo + ao);
        }
#pragma unroll
        for (int nt2 = 0; nt2 < 16; ++nt2) {
#pragma unroll
            for (int kt = 0; kt < 2; ++kt) {
                const size_t mo = ((size_t)hh * D + nt2 * 16 + l15) * D +
                                  kc * 64 + kt * 32 + quad * 8;
                short8 Bh = *(const short8*)(Mt_hi + mo);
                short8 Bl = *(const short8*)(Mt_lo + mo);
                qac[nt2] = MFMA_BF(Ah[kt], Bh, qac[nt2]);
                qac[nt2] = MFMA_BF(Al[kt], Bh, qac[nt2]);
                qac[nt2] = MFMA_BF(Ah[kt], Bl, qac[nt2]);
            }
        }
    }

    // repack Q' C-layout -> bf16 hi/lo A-frags via fp32 scratch in buf0
    // (wave-private rows, pitch 68 f32; 34.8 KB < 49 KB buf0)
    short8 Qhi[8], Qlo[8];
    {
        float* qscr = (float*)lds;
        for (int c = 0; c < 4; ++c) {
#pragma unroll
            for (int j = 0; j < 4; ++j)
#pragma unroll
                for (int r = 0; r < 4; ++r)
                    qscr[(wv * 16 + quad * 4 + r) * 68 + j * 16 + l15] = qac[c * 4 + j][r];
#pragma unroll
            for (int kt = 0; kt < 2; ++kt) {
                const float* pr = &qscr[(wv * 16 + l15) * 68 + kt * 32 + quad * 8];
                float ftmp[8];
                *(float4*)&ftmp[0] = *(const float4*)pr;
                *(float4*)&ftmp[4] = *(const float4*)(pr + 4);
                short8 hi, lo;
#pragma unroll
                for (int e = 0; e < 8; ++e) {
                    unsigned short hb = bf16_rtne(ftmp[e]);
                    hi[e] = (short)hb;
                    lo[e] = (short)bf16_rtne(ftmp[e] - bf16_tof(hb));
                }
                Qhi[c * 2 + kt] = hi;
                Qlo[c * 2 + kt] = lo;
            }
        }
    }
    __syncthreads();   // all waves done with Q' scratch before DMA into buf0

    // ---- DMA issue helper (tile n0 -> buf)
    auto issue_tile = [&](char* buf, int n0) {
        ushort* dh = (ushort*)buf;
        ushort* dl = (ushort*)(buf + 16384);
        ushort* dT = (ushort*)(buf + 32768);
#pragma unroll
        for (int i = 0; i < 2; ++i) {
            const int slot = wv * 128 + i * 64 + lane;
            const int row  = slot >> 5;
            const int p    = slot & 31;
            const int c    = p ^ (row & 7);
            const size_t go = (size_t)(n0 + row) * 256 + c * 8;
            const size_t lo_ = (size_t)(wv * 128 + i * 64) * 8;
            async16(dh + lo_, hbh + go);
            async16(dl + lo_, hbl + go);
        }
#pragma unroll
        for (int i = 0; i < 2; ++i) {
            const int slot = wv * 128 + i * 64 + lane;
            const int row  = slot >> 2;
            const int p    = slot & 3;
            const int c    = p ^ ((row >> 2) & 3);
            async16(dT + (size_t)(wv * 128 + i * 64) * 8,
                    hTb + (size_t)row * 1024 + n0 + c * 8);
        }
    };

    // prologue: tiles 0 and 1 in flight, then drain once
    issue_tile(lds,         0);
    issue_tile(lds + 49152, 32);
    __syncthreads();

    // ---- Phase 1: pipelined flash loop over 32 n-tiles of 32 rows
    floatx4 zac[16];
#pragma unroll
    for (int i = 0; i < 16; ++i) zac[i] = (floatx4){0.f, 0.f, 0.f, 0.f};
    floatx4 zacZ = (floatx4){0.f, 0.f, 0.f, 0.f};   // Zm row-sums (MFMA ones)
    floatx4 zacE = (floatx4){0.f, 0.f, 0.f, 0.f};   // Za row-sums (MFMA ones)
    float mx[4] = {-INFINITY, -INFINITY, -INFINITY, -INFINITY};

    short8 onesf;
#pragma unroll
    for (int e = 0; e < 8; ++e) onesf[e] = (short)0x3F80;   // bf16 1.0

    const unsigned* mbr = mbits + ((size_t)b * AG + aw + quad * 4) * (SEQ / 32);

    for (int nt = 0; nt < 32; ++nt) {
        char* cur = lds + (size_t)(nt & 1) * 49152;
        ushort* hS_hi = (ushort*)cur;
        ushort* hS_lo = (ushort*)(cur + 16384);
        ushort* hTS   = (ushort*)(cur + 32768);

        // S = Q' @ h^T  (split-bf16 x3; swizzled b128 reads; 4 acc chains)
        floatx4 sacH[2], sacL[2];
        sacH[0] = (floatx4){0.f, 0.f, 0.f, 0.f};
        sacH[1] = (floatx4){0.f, 0.f, 0.f, 0.f};
        sacL[0] = (floatx4){0.f, 0.f, 0.f, 0.f};
        sacL[1] = (floatx4){0.f, 0.f, 0.f, 0.f};
        __builtin_amdgcn_s_setprio(1);
#pragma unroll
        for (int ks = 0; ks < 8; ++ks) {
            const int cg = ks * 4 + quad;
#pragma unroll
            for (int ntile = 0; ntile < 2; ++ntile) {
                const int row = ntile * 16 + l15;
                const int off = row * 256 + (cg ^ (row & 7)) * 8;
                short8 Bh = *(const short8*)&hS_hi[off];
                short8 Bl = *(const short8*)&hS_lo[off];
                sacH[ntile] = MFMA_BF(Qhi[ks], Bh, sacH[ntile]);
                sacL[ntile] = MFMA_BF(Qlo[ks], Bh, sacL[ntile]);
                sacL[ntile] = MFMA_BF(Qhi[ks], Bl, sacL[ntile]);
            }
        }
        __builtin_amdgcn_s_setprio(0);

        // logits for this wave's 16x32 tile (4 rows per lane)
        float l0[4], l1[4];
#pragma unroll
        for (int r = 0; r < 4; ++r) {
            l0[r] = (sacH[0][r] + sacL[0][r]) * SCALE;
            l1[r] = (sacH[1][r] + sacL[1][r]) * SCALE;
        }

        // per-row tile max: 4-deep 16-lane butterfly, 4 independent chains
        float mt[4];
#pragma unroll
        for (int r = 0; r < 4; ++r) mt[r] = fmaxf(l0[r], l1[r]);
#pragma unroll
        for (int off = 1; off < 16; off <<= 1) {
#pragma unroll
            for (int r = 0; r < 4; ++r)
                mt[r] = fmaxf(mt[r], __shfl_xor(mt[r], off));
        }

        // deferred rescale (rare, wave-uniform branch)
        const bool need = (mt[0] > mx[0] + 8.0f) || (mt[1] > mx[1] + 8.0f) ||
                          (mt[2] > mx[2] + 8.0f) || (mt[3] > mx[3] + 8.0f);
        if (__any(need)) {
            float alr[4];
#pragma unroll
            for (int r = 0; r < 4; ++r) {
                const float mxn = fmaxf(mx[r], mt[r]);
                alr[r] = __expf(mx[r] - mxn);
                mx[r] = mxn;
            }
#pragma unroll
            for (int dt = 0; dt < 16; ++dt) {
                zac[dt][0] *= alr[0]; zac[dt][1] *= alr[1];
                zac[dt][2] *= alr[2]; zac[dt][3] *= alr[3];
            }
            zacZ[0] *= alr[0]; zacZ[1] *= alr[1];
            zacZ[2] *= alr[2]; zacZ[3] *= alr[3];
            zacE[0] *= alr[0]; zacE[1] *= alr[1];
            zacE[2] *= alr[2]; zacE[3] *= alr[3];
        }

        // masked p and unmasked e -> bf16 LDS frags (no lane reductions)
#pragma unroll
        for (int r = 0; r < 4; ++r) {
            const unsigned w0 = mbr[r * (SEQ / 32) + nt];
            const float e0 = __expf(l0[r] - mx[r]);
            const float e1 = __expf(l1[r] - mx[r]);
            const float p0 = ((w0 >> l15) & 1u)        ? e0 : 0.f;
            const float p1 = ((w0 >> (16 + l15)) & 1u) ? e1 : 0.f;
            const int row = wv * 16 + quad * 4 + r;
            pP[row * 40 + l15]      = bf16_rtne(p0);
            pP[row * 40 + 16 + l15] = bf16_rtne(p1);
            pE[row * 40 + l15]      = bf16_rtne(e0);
            pE[row * 40 + 16 + l15] = bf16_rtne(e1);
        }

        // row-sums via MFMA with immediate ones B-frag: Zm (masked), Za (raw)
        short8 Pf = *(const short8*)&pP[(wv * 16 + l15) * 40 + quad * 8];
        short8 Ef = *(const short8*)&pE[(wv * 16 + l15) * 40 + quad * 8];
        zacZ = MFMA_BF(Pf, onesf, zacZ);
        zacE = MFMA_BF(Ef, onesf, zacE);

        // z += P @ h : P A-frag (wave-private pP), hTS B-frags (swizzled)
        __builtin_amdgcn_s_setprio(1);
#pragma unroll
        for (int dt = 0; dt < 16; ++dt) {
            const int row = dt * 16 + l15;
            const int p   = quad ^ ((row >> 2) & 3);
            short8 Bf = *(const short8*)&hTS[row * 32 + p * 8];
            zac[dt] = MFMA_BF(Pf, Bf, zac[dt]);
        }
        __builtin_amdgcn_s_setprio(0);

        // barrier: everyone done reading cur; DMA(nt+1) — issued one full
        // iteration ago — drains here with a tile's worth of slack.
        __syncthreads();
        if (nt + 2 < 32) issue_tile(cur, (nt + 2) * 32);
    }

    // epilogue: z_bf16 = z / (Zm + EPS*Za)
#pragma unroll
    for (int r = 0; r < 4; ++r) {
        const int a = aw + quad * 4 + r;
        const float inv = 1.0f / (zacZ[r] + EPS * zacE[r]);
        ushort* zr = zout + (((size_t)b * NH + hh) * AG + a) * D;
#pragma unroll
        for (int dt = 0; dt < 16; ++dt)
            zr[dt * 16 + l15] = bf16_rtne(zac[dt][r] * inv);
    }
}

// ---------------------------------------------------------------------------
// out v18: 64x64 tile + XCD swizzle + z16 A-operand LDS-staged via DMA
// double-buffer (proven +9 us vs global-operand MFMA at 2 waves/SIMD).
// ---------------------------------------------------------------------------
__global__ __launch_bounds__(256) void out_mfma(
    const ushort* __restrict__ z16, const ushort* __restrict__ WVt,
    float* __restrict__ out)
{
    __shared__ __align__(16) char olds[65536];
    const int t    = threadIdx.x;
    const int wv   = t >> 6;
    const int lane = t & 63;
    const int l15  = lane & 15;
    const int quad = lane >> 4;
    const int f    = blockIdx.x;               // 512 blocks
    const int b    = (f & 7) + 8 * (f >> 7);   // same-b -> same XCD
    const int mid  = (f >> 3) & 15;
    const int e0   = (mid & 3) * 64;
    const int a0   = (mid >> 2) * 64;
    const int aw   = a0 + wv * 16;

    const ushort* zb = z16 + (size_t)b * NH * AG * D;

    // DMA head-hh tile (rows a0..a0+63, all 256 d) into buf, XOR-swizzled:
    // LDS slot (row, p) holds global col-group c = p ^ (row & 7).
    auto stage = [&](char* buf, int hh) {
        ushort* dst = (ushort*)buf;
        const ushort* src = zb + (size_t)hh * AG * D;
#pragma unroll
        for (int i = 0; i < 8; ++i) {
            const int slot = i * 256 + t;        // 0..2047
            const int row  = slot >> 5;          // 0..63
            const int p    = slot & 31;
            const int c    = p ^ (row & 7);
            async16(dst + (size_t)slot * 8,
                    src + (size_t)(a0 + row) * D + c * 8);
        }
    };

    floatx4 acc[4];
#pragma unroll
    for (int i = 0; i < 4; ++i) acc[i] = (floatx4){0.f, 0.f, 0.f, 0.f};

    stage(olds, 0);
    __syncthreads();

    for (int hh = 0; hh < 8; ++hh) {
        char* cur = olds + (size_t)(hh & 1) * 32768;
        if (hh + 1 < 8) stage(olds + (size_t)((hh + 1) & 1) * 32768, hh + 1);

        ushort* zt = (ushort*)cur;
        const int lrow = wv * 16 + l15;          // LDS row (local a)
#pragma unroll
        for (int ci = 0; ci < 8; ++ci) {
            const int d0 = ci * 32;
            const int g  = ci * 4 + quad;        // global col-group 0..31
            short8 Af = *(const short8*)&zt[(size_t)lrow * 256 +
                                            (g ^ (lrow & 7)) * 8];
#pragma unroll
            for (int et = 0; et < 4; ++et) {
                short8 Bf = *(const short8*)(WVt +
                    ((size_t)hh * D + e0 + et * 16 + l15) * D + d0 + quad * 8);
                acc[et] = MFMA_BF(Af, Bf, acc[et]);
            }
        }
        // implicit vmcnt(0) completes DMA(hh+1); all waves done reading cur
        __syncthreads();
    }

#pragma unroll
    for (int et = 0; et < 4; ++et)
#pragma unroll
        for (int r = 0; r < 4; ++r)
            out[((size_t)b * AG + aw + quad * 4 + r) * D + e0 + et * 16 + l15] =
                acc[et][r] * 0.125f;
}

// ---------------------------------------------------------------------------
extern "C" void kernel_launch(void* const* d_in, const int* in_sizes, int n_in,
                              void* d_out, int out_size, void* d_ws, size_t ws_size,
                              hipStream_t stream)
{
    (void)in_sizes; (void)n_in; (void)out_size; (void)ws_size;
    const float* x     = (const float*)d_in[0];
    const float* m     = (const float*)d_in[1];
    const float* W_enc = (const float*)d_in[2];
    const float* b_enc = (const float*)d_in[3];
    const float* WQ    = (const float*)d_in[4];
    const float* WK    = (const float*)d_in[5];
    const float* WV    = (const float*)d_in[6];
    float* out = (float*)d_out;
    char* ws = (char*)d_ws;

    ushort*   h_hi  = (ushort*)(ws + HHI_OFF);
    ushort*   h_lo  = (ushort*)(ws + HLO_OFF);
    ushort*   hT    = (ushort*)(ws + HT_OFF);
    ushort*   Mt_hi = (ushort*)(ws + MTHI_OFF);
    ushort*   Mt_lo = (ushort*)(ws + MTLO_OFF);
    unsigned* mbits = (unsigned*)(ws + MB_OFF);
    ushort*   WVt   = (ushort*)(ws + WVT_OFF);
    ushort*   z16   = (ushort*)(ws + Z16_OFF);

    enc_prep<<<dim3(3328, 1, 1), dim3(256), 0, stream>>>(
        x, W_enc, b_enc, h_hi, h_lo, hT,
        m, mbits, WV, WVt, WQ, WK, Mt_hi, Mt_lo);
    attn_mfma<<<dim3(512, 1, 1), dim3(512), 0, stream>>>(
        h_hi, h_lo, hT, Mt_hi, Mt_lo, mbits, z16);
    out_mfma<<<dim3(512, 1, 1), dim3(256), 0, stream>>>(z16, WVt, out);
}

// Round 15
// 509.883 us; speedup vs baseline: 1.5407x; 1.0060x over previous
//
#include <hip/hip_runtime.h>
#include <math.h>

namespace {
constexpr int B_N  = 32;
constexpr int SEQ  = 1024;
constexpr int AG   = 256;
constexpr int D    = 256;
constexpr int NH   = 8;
constexpr float SCALE = 0.0625f;
constexpr float EPS   = 1e-12f;

// workspace byte offsets (total ~88 MB)
constexpr size_t HHI_OFF  = 0;          // ushort(bf16) B*SEQ*D = 16 MB
constexpr size_t HLO_OFF  = 16777216;   // ushort(bf16) B*SEQ*D = 16 MB
constexpr size_t HT_OFF   = 33554432;   // ushort(bf16) B*D*SEQ = 16 MB
constexpr size_t MTHI_OFF = 50331648;   // ushort NH*D*D = 1 MB
constexpr size_t MTLO_OFF = 51380224;   // ushort NH*D*D = 1 MB
constexpr size_t MB_OFF   = 52428800;   // u32 B*AG*SEQ/32 = 1 MB
constexpr size_t WVT_OFF  = 53477376;   // ushort NH*D*D = 1 MB
constexpr size_t Z16_OFF  = 54525952;   // ushort B*NH*AG*D = 33.5 MB
}

typedef __attribute__((ext_vector_type(8))) short short8;
typedef __attribute__((ext_vector_type(4))) float floatx4;
#define MFMA_BF(A,B,C) __builtin_amdgcn_mfma_f32_16x16x32_bf16(A,B,C,0,0,0)

__device__ __forceinline__ unsigned short bf16_rtne(float f) {
    unsigned u = __float_as_uint(f);
    u += 0x7fffu + ((u >> 16) & 1u);
    return (unsigned short)(u >> 16);
}
__device__ __forceinline__ float bf16_tof(unsigned short h) {
    return __uint_as_float(((unsigned)h) << 16);
}
// async global->LDS DMA, 16 B/lane; LDS dst = wave-uniform base + lane*16
__device__ __forceinline__ void async16(void* lds, const void* g) {
    __builtin_amdgcn_global_load_lds(
        (const __attribute__((address_space(1))) unsigned int*)g,
        (__attribute__((address_space(3))) unsigned int*)lds,
        16, 0, 0);
}

// ---------------------------------------------------------------------------
// enc_prep v21: encoder x-reuse. One enc block (v<512) computes its 64 rows
// x ALL 256 output cols: x row-panel loaded & lrelu/split-converted ONCE
// (was 4x across col-split blocks -> 384 MB of L3 re-reads + 4x conversion
// VALU). W tile [256][40] hi/lo in LDS (51200 B total -> 3 blocks/CU, 12
// waves). Per-wave acc = 16 frags (64 regs, proven budget). Epilogue loops
// the proven 64-col write + hT-transpose over 4 panels via reused LDS.
// Accumulation order over k unchanged -> identical numerics.
//   v <  512  : encoder, row0 = v*64
//   v < 1536  : maskbits
//   v < 1664  : wvt
//   else      : mprep
// ---------------------------------------------------------------------------
__global__ __launch_bounds__(256) void enc_prep(
    const float* __restrict__ x, const float* __restrict__ W_enc,
    const float* __restrict__ b_enc,
    ushort* __restrict__ h_hi, ushort* __restrict__ h_lo,
    ushort* __restrict__ hT,
    const float* __restrict__ m, unsigned* __restrict__ mb,
    const float* __restrict__ WV, ushort* __restrict__ WVt,
    const float* __restrict__ WQ, const float* __restrict__ WK,
    ushort* __restrict__ Mt_hi, ushort* __restrict__ Mt_lo)
{
    __shared__ __align__(16) char slds[51200];
    const int t = threadIdx.x;
    const int v = blockIdx.x;

    if (v < 512) {
        // ---- encoder: h = lrelu(x)@W_enc^T + b (split-bf16 x3 MFMA) + hT
        ushort (*Axh)[40] = (ushort(*)[40])(slds);            // 5120 B
        ushort (*Axl)[40] = (ushort(*)[40])(slds + 5120);     // 5120 B
        ushort (*Bwh)[40] = (ushort(*)[40])(slds + 10240);    // 20480 B
        ushort (*Bwl)[40] = (ushort(*)[40])(slds + 30720);    // 20480 B

        const int wv   = t >> 6;
        const int lane = t & 63;
        const int l15  = lane & 15;
        const int quad = lane >> 4;
        const int row0 = v * 64;

        floatx4 acc[16];
#pragma unroll
        for (int i = 0; i < 16; ++i) acc[i] = (floatx4){0.f, 0.f, 0.f, 0.f};

        for (int k0 = 0; k0 < 256; k0 += 32) {
            __syncthreads();
            {
                // x tile: 64 rows x 32 k; thread: row t>>2, 8 floats
                const int r = t >> 2, s = (t & 3) * 8;
                float f[8];
                *(float4*)&f[0] = *(const float4*)(x + (size_t)(row0 + r) * 256 + k0 + s);
                *(float4*)&f[4] = *(const float4*)(x + (size_t)(row0 + r) * 256 + k0 + s + 4);
                short8 hi8, lo8;
#pragma unroll
                for (int e = 0; e < 8; ++e) {
                    float vv = f[e] > 0.f ? f[e] : 0.01f * f[e];
                    unsigned short hb = bf16_rtne(vv);
                    hi8[e] = (short)hb;
                    lo8[e] = (short)bf16_rtne(vv - bf16_tof(hb));
                }
                *(short8*)&Axh[r][s] = hi8;
                *(short8*)&Axl[r][s] = lo8;
                // W tile: 256 rows x 32 k; thread: row t, 4 chunks of 8
#pragma unroll
                for (int ch = 0; ch < 4; ++ch) {
                    const int ws = ch * 8;
                    *(float4*)&f[0] = *(const float4*)(W_enc + (size_t)t * 256 + k0 + ws);
                    *(float4*)&f[4] = *(const float4*)(W_enc + (size_t)t * 256 + k0 + ws + 4);
#pragma unroll
                    for (int e = 0; e < 8; ++e) {
                        unsigned short hb = bf16_rtne(f[e]);
                        hi8[e] = (short)hb;
                        lo8[e] = (short)bf16_rtne(f[e] - bf16_tof(hb));
                    }
                    *(short8*)&Bwh[t][ws] = hi8;
                    *(short8*)&Bwl[t][ws] = lo8;
                }
            }
            __syncthreads();

            short8 Af  = *(const short8*)&Axh[wv * 16 + l15][quad * 8];
            short8 Afl = *(const short8*)&Axl[wv * 16 + l15][quad * 8];
#pragma unroll
            for (int ot = 0; ot < 16; ++ot) {
                short8 Bf  = *(const short8*)&Bwh[ot * 16 + l15][quad * 8];
                short8 Bfl = *(const short8*)&Bwl[ot * 16 + l15][quad * 8];
                acc[ot] = MFMA_BF(Af,  Bf,  acc[ot]);
                acc[ot] = MFMA_BF(Afl, Bf,  acc[ot]);
                acc[ot] = MFMA_BF(Af,  Bfl, acc[ot]);
            }
        }

        // epilogue: 4 col-panels of 64 through reused LDS staging
        ushort (*Th)[72] = (ushort(*)[72])(slds);            // 9216 B
        ushort (*Tl)[72] = (ushort(*)[72])(slds + 9216);     // 9216 B
        const int bq = v >> 4;             // batch
        const int n0 = (v & 15) * 64;      // n-offset within batch
        for (int cp = 0; cp < 4; ++cp) {
            __syncthreads();   // LDS free (k-loop or previous panel done)
#pragma unroll
            for (int et = 0; et < 4; ++et) {
                const int col = et * 16 + l15;
                const float bb = b_enc[cp * 64 + col];
#pragma unroll
                for (int r = 0; r < 4; ++r) {
                    const int row = wv * 16 + quad * 4 + r;
                    const float vv = acc[cp * 4 + et][r] + bb;
                    const unsigned short hb = bf16_rtne(vv);
                    Th[row][col] = hb;
                    Tl[row][col] = bf16_rtne(vv - bf16_tof(hb));
                }
            }
            __syncthreads();
            {
                const int r = t >> 2, c0 = (t & 3) * 16;
                ushort* dh = h_hi + (size_t)(row0 + r) * 256 + cp * 64 + c0;
                ushort* dl = h_lo + (size_t)(row0 + r) * 256 + cp * 64 + c0;
                *(short8*)dh       = *(const short8*)&Th[r][c0];
                *(short8*)(dh + 8) = *(const short8*)&Th[r][c0 + 8];
                *(short8*)dl       = *(const short8*)&Tl[r][c0];
                *(short8*)(dl + 8) = *(const short8*)&Tl[r][c0 + 8];
            }
            {
                const int dd = t >> 2, seg = (t & 3) * 16;
                ushort tmp[16];
#pragma unroll
                for (int j = 0; j < 16; ++j) tmp[j] = Th[seg + j][dd];
                ushort* dst = hT + ((size_t)(bq * 256 + cp * 64 + dd)) * 1024 + n0 + seg;
                *(short8*)dst       = *(short8*)&tmp[0];
                *(short8*)(dst + 8) = *(short8*)&tmp[8];
            }
        }
    } else if (v < 1536) {
        // ---- maskbits
        const int idx = (v - 512) * 256 + t;
        const float4* src = (const float4*)(m + (size_t)idx * 32);
        unsigned wbits = 0;
#pragma unroll
        for (int i = 0; i < 8; ++i) {
            float4 vv = src[i];
            wbits |= (vv.x > 0.5f ? 1u : 0u) << (i * 4 + 0);
            wbits |= (vv.y > 0.5f ? 1u : 0u) << (i * 4 + 1);
            wbits |= (vv.z > 0.5f ? 1u : 0u) << (i * 4 + 2);
            wbits |= (vv.w > 0.5f ? 1u : 0u) << (i * 4 + 3);
        }
        mb[idx] = wbits;
    } else if (v < 1664) {
        // ---- wvt: WVt[h][e][d] = bf16(WV[h][d][e]); pitch 68 f32
        float (*T)[68] = (float(*)[68])slds;     // 17408 B
        const int v2 = v - 1536;
        const int d0 = (v2 & 3) * 64, e0 = ((v2 >> 2) & 3) * 64, h = v2 >> 4;
        {
            const int r = t >> 2, c = (t & 3) * 16;
            const float* src = WV + ((size_t)(h * 256 + d0 + r)) * 256 + e0 + c;
#pragma unroll
            for (int j = 0; j < 4; ++j)
                *(float4*)&T[r][c + j * 4] = *(const float4*)(src + j * 4);
        }
        __syncthreads();
        {
            const int ee = t >> 2, seg = (t & 3) * 16;
            ushort tmp[16];
#pragma unroll
            for (int j = 0; j < 16; ++j) tmp[j] = bf16_rtne(T[seg + j][ee]);
            ushort* dst = WVt + ((size_t)(h * 256 + e0 + ee)) * 256 + d0 + seg;
            *(short8*)dst       = *(short8*)&tmp[0];
            *(short8*)(dst + 8) = *(short8*)&tmp[8];
        }
    } else {
        // ---- mprep: Mt_h[d'][d] = (WQ_h @ WK_h^T)[d][d'] -> bf16 hi/lo
        float (*AsT)[68] = (float(*)[68])slds;           // 8704 B
        float (*BsT)[68] = (float(*)[68])(slds + 8704);  // 8704 B
        const int v3 = v - 1664;
        const int tx = t & 15, ty = t >> 4;
        const int col0 = (v3 & 3) * 64;
        const int row0 = ((v3 >> 2) & 3) * 64;
        const int hz   = v3 >> 4;
        const float* A  = WK + (size_t)hz * 256 * 256;
        const float* Bm = WQ + (size_t)hz * 256 * 256;
        ushort* Chi = Mt_hi + (size_t)hz * 256 * 256;
        ushort* Clo = Mt_lo + (size_t)hz * 256 * 256;

        float acc[4][4];
#pragma unroll
        for (int r = 0; r < 4; ++r)
#pragma unroll
            for (int c = 0; c < 4; ++c) acc[r][c] = 0.f;

        for (int k0 = 0; k0 < 256; k0 += 32) {
            __syncthreads();
#pragma unroll
            for (int ss = 0; ss < 2; ++ss) {
                int flat = t + 256 * ss;
                int rr = flat >> 3, k4 = flat & 7;
                float4 vv = *(const float4*)(A + (size_t)(row0 + rr) * 256 + k0 + k4 * 4);
                AsT[k4*4+0][rr] = vv.x; AsT[k4*4+1][rr] = vv.y;
                AsT[k4*4+2][rr] = vv.z; AsT[k4*4+3][rr] = vv.w;
                float4 wv = *(const float4*)(Bm + (size_t)(col0 + rr) * 256 + k0 + k4 * 4);
                BsT[k4*4+0][rr] = wv.x; BsT[k4*4+1][rr] = wv.y;
                BsT[k4*4+2][rr] = wv.z; BsT[k4*4+3][rr] = wv.w;
            }
            __syncthreads();
#pragma unroll 8
            for (int kk = 0; kk < 32; ++kk) {
                float4 a4 = *(const float4*)&AsT[kk][ty * 4];
                float4 b4 = *(const float4*)&BsT[kk][tx * 4];
                const float ar[4] = {a4.x, a4.y, a4.z, a4.w};
                const float bc[4] = {b4.x, b4.y, b4.z, b4.w};
#pragma unroll
                for (int r = 0; r < 4; ++r)
#pragma unroll
                    for (int c = 0; c < 4; ++c)
                        acc[r][c] = fmaf(ar[r], bc[c], acc[r][c]);
            }
        }
#pragma unroll
        for (int r = 0; r < 4; ++r) {
            const int row = row0 + ty * 4 + r;
            ushort hi4[4], lo4[4];
#pragma unroll
            for (int c = 0; c < 4; ++c) {
                float vv = acc[r][c];
                hi4[c] = bf16_rtne(vv);
                lo4[c] = bf16_rtne(vv - bf16_tof(hi4[c]));
            }
            *(ushort4*)(Chi + (size_t)row * 256 + col0 + tx * 4) =
                make_ushort4(hi4[0], hi4[1], hi4[2], hi4[3]);
            *(ushort4*)(Clo + (size_t)row * 256 + col0 + tx * 4) =
                make_ushort4(lo4[0], lo4[1], lo4[2], lo4[3]);
        }
    }
}

// ---------------------------------------------------------------------------
// Attention (proven 330-334 us): v10 structure + neutral setprio. Register-
// pinned at 2 waves/SIMD; MFMA operands must come from LDS (v14/v19 measured).
// ---------------------------------------------------------------------------
__global__ __launch_bounds__(512, 2) void attn_mfma(
    const ushort* __restrict__ h_hi, const ushort* __restrict__ h_lo,
    const ushort* __restrict__ hT,   const ushort* __restrict__ Mt_hi,
    const ushort* __restrict__ Mt_lo, const unsigned* __restrict__ mbits,
    ushort* __restrict__ zout)
{
    // buf k at k*49152: hS_hi 16384 | hS_lo 16384 | hTS 16384 ;
    // pP at 98304 (10240) ; pE at 108544 (10240)  -> 118784 B total
    __shared__ __align__(16) char lds[118784];
    ushort* pP = (ushort*)(lds + 98304);   // [128][40] bf16 masked p
    ushort* pE = (ushort*)(lds + 108544);  // [128][40] bf16 unmasked e

    const int t    = threadIdx.x;
    const int wv   = t >> 6;          // 0..7
    const int lane = t & 63;
    const int l15  = lane & 15;
    const int quad = lane >> 4;
    const int f    = blockIdx.x;      // 512 blocks
    const int b    = (f & 7) + 8 * (f >> 7);
    const int mid  = (f >> 3) & 15;
    const int hh   = (mid >> 2) * 2 + (wv >> 2);   // head per wave
    const int a0   = (mid & 3) * 64;
    const int aw   = a0 + (wv & 3) * 16;           // a-subtile per wave

    const ushort* hbh = h_hi + (size_t)b * SEQ * D;
    const ushort* hbl = h_lo + (size_t)b * SEQ * D;
    const ushort* hTb = hT   + (size_t)b * D * SEQ;

    // ---- Phase 0: Q' = ha @ Mt^T (split-bf16 x3), C-layout fp32 tiles
    floatx4 qac[16];
#pragma unroll
    for (int i = 0; i < 16; ++i) qac[i] = (floatx4){0.f, 0.f, 0.f, 0.f};

    for (int kc = 0; kc < 4; ++kc) {
        short8 Ah[2], Al[2];
#pragma unroll
        for (int kt = 0; kt < 2; ++kt) {
            const size_t ao = ((size_t)b * SEQ + aw + l15) * D +
                              kc * 64 + kt * 32 + quad * 8;
            Ah[kt] = *(const short8*)(h_hi + ao);
            Al[kt] = *(const short8*)(h_lo + ao);
        }
#pragma unroll
        for (int nt2 = 0; nt2 < 16; ++nt2) {
#pragma unroll
            for (int kt = 0; kt < 2; ++kt) {
                const size_t mo = ((size_t)hh * D + nt2 * 16 + l15) * D +
                                  kc * 64 + kt * 32 + quad * 8;
                short8 Bh = *(const short8*)(Mt_hi + mo);
                short8 Bl = *(const short8*)(Mt_lo + mo);
                qac[nt2] = MFMA_BF(Ah[kt], Bh, qac[nt2]);
                qac[nt2] = MFMA_BF(Al[kt], Bh, qac[nt2]);
                qac[nt2] = MFMA_BF(Ah[kt], Bl, qac[nt2]);
            }
        }
    }

    // repack Q' C-layout -> bf16 hi/lo A-frags via fp32 scratch in buf0
    // (wave-private rows, pitch 68 f32; 34.8 KB < 49 KB buf0)
    short8 Qhi[8], Qlo[8];
    {
        float* qscr = (float*)lds;
        for (int c = 0; c < 4; ++c) {
#pragma unroll
            for (int j = 0; j < 4; ++j)
#pragma unroll
                for (int r = 0; r < 4; ++r)
                    qscr[(wv * 16 + quad * 4 + r) * 68 + j * 16 + l15] = qac[c * 4 + j][r];
#pragma unroll
            for (int kt = 0; kt < 2; ++kt) {
                const float* pr = &qscr[(wv * 16 + l15) * 68 + kt * 32 + quad * 8];
                float ftmp[8];
                *(float4*)&ftmp[0] = *(const float4*)pr;
                *(float4*)&ftmp[4] = *(const float4*)(pr + 4);
                short8 hi, lo;
#pragma unroll
                for (int e = 0; e < 8; ++e) {
                    unsigned short hb = bf16_rtne(ftmp[e]);
                    hi[e] = (short)hb;
                    lo[e] = (short)bf16_rtne(ftmp[e] - bf16_tof(hb));
                }
                Qhi[c * 2 + kt] = hi;
                Qlo[c * 2 + kt] = lo;
            }
        }
    }
    __syncthreads();   // all waves done with Q' scratch before DMA into buf0

    // ---- DMA issue helper (tile n0 -> buf)
    auto issue_tile = [&](char* buf, int n0) {
        ushort* dh = (ushort*)buf;
        ushort* dl = (ushort*)(buf + 16384);
        ushort* dT = (ushort*)(buf + 32768);
#pragma unroll
        for (int i = 0; i < 2; ++i) {
            const int slot = wv * 128 + i * 64 + lane;
            const int row  = slot >> 5;
            const int p    = slot & 31;
            const int c    = p ^ (row & 7);
            const size_t go = (size_t)(n0 + row) * 256 + c * 8;
            const size_t lo_ = (size_t)(wv * 128 + i * 64) * 8;
            async16(dh + lo_, hbh + go);
            async16(dl + lo_, hbl + go);
        }
#pragma unroll
        for (int i = 0; i < 2; ++i) {
            const int slot = wv * 128 + i * 64 + lane;
            const int row  = slot >> 2;
            const int p    = slot & 3;
            const int c    = p ^ ((row >> 2) & 3);
            async16(dT + (size_t)(wv * 128 + i * 64) * 8,
                    hTb + (size_t)row * 1024 + n0 + c * 8);
        }
    };

    // prologue: tiles 0 and 1 in flight, then drain once
    issue_tile(lds,         0);
    issue_tile(lds + 49152, 32);
    __syncthreads();

    // ---- Phase 1: pipelined flash loop over 32 n-tiles of 32 rows
    floatx4 zac[16];
#pragma unroll
    for (int i = 0; i < 16; ++i) zac[i] = (floatx4){0.f, 0.f, 0.f, 0.f};
    floatx4 zacZ = (floatx4){0.f, 0.f, 0.f, 0.f};   // Zm row-sums (MFMA ones)
    floatx4 zacE = (floatx4){0.f, 0.f, 0.f, 0.f};   // Za row-sums (MFMA ones)
    float mx[4] = {-INFINITY, -INFINITY, -INFINITY, -INFINITY};

    short8 onesf;
#pragma unroll
    for (int e = 0; e < 8; ++e) onesf[e] = (short)0x3F80;   // bf16 1.0

    const unsigned* mbr = mbits + ((size_t)b * AG + aw + quad * 4) * (SEQ / 32);

    for (int nt = 0; nt < 32; ++nt) {
        char* cur = lds + (size_t)(nt & 1) * 49152;
        ushort* hS_hi = (ushort*)cur;
        ushort* hS_lo = (ushort*)(cur + 16384);
        ushort* hTS   = (ushort*)(cur + 32768);

        // S = Q' @ h^T  (split-bf16 x3; swizzled b128 reads; 4 acc chains)
        floatx4 sacH[2], sacL[2];
        sacH[0] = (floatx4){0.f, 0.f, 0.f, 0.f};
        sacH[1] = (floatx4){0.f, 0.f, 0.f, 0.f};
        sacL[0] = (floatx4){0.f, 0.f, 0.f, 0.f};
        sacL[1] = (floatx4){0.f, 0.f, 0.f, 0.f};
        __builtin_amdgcn_s_setprio(1);
#pragma unroll
        for (int ks = 0; ks < 8; ++ks) {
            const int cg = ks * 4 + quad;
#pragma unroll
            for (int ntile = 0; ntile < 2; ++ntile) {
                const int row = ntile * 16 + l15;
                const int off = row * 256 + (cg ^ (row & 7)) * 8;
                short8 Bh = *(const short8*)&hS_hi[off];
                short8 Bl = *(const short8*)&hS_lo[off];
                sacH[ntile] = MFMA_BF(Qhi[ks], Bh, sacH[ntile]);
                sacL[ntile] = MFMA_BF(Qlo[ks], Bh, sacL[ntile]);
                sacL[ntile] = MFMA_BF(Qhi[ks], Bl, sacL[ntile]);
            }
        }
        __builtin_amdgcn_s_setprio(0);

        // logits for this wave's 16x32 tile (4 rows per lane)
        float l0[4], l1[4];
#pragma unroll
        for (int r = 0; r < 4; ++r) {
            l0[r] = (sacH[0][r] + sacL[0][r]) * SCALE;
            l1[r] = (sacH[1][r] + sacL[1][r]) * SCALE;
        }

        // per-row tile max: 4-deep 16-lane butterfly, 4 independent chains
        float mt[4];
#pragma unroll
        for (int r = 0; r < 4; ++r) mt[r] = fmaxf(l0[r], l1[r]);
#pragma unroll
        for (int off = 1; off < 16; off <<= 1) {
#pragma unroll
            for (int r = 0; r < 4; ++r)
                mt[r] = fmaxf(mt[r], __shfl_xor(mt[r], off));
        }

        // deferred rescale (rare, wave-uniform branch)
        const bool need = (mt[0] > mx[0] + 8.0f) || (mt[1] > mx[1] + 8.0f) ||
                          (mt[2] > mx[2] + 8.0f) || (mt[3] > mx[3] + 8.0f);
        if (__any(need)) {
            float alr[4];
#pragma unroll
            for (int r = 0; r < 4; ++r) {
                const float mxn = fmaxf(mx[r], mt[r]);
                alr[r] = __expf(mx[r] - mxn);
                mx[r] = mxn;
            }
#pragma unroll
            for (int dt = 0; dt < 16; ++dt) {
                zac[dt][0] *= alr[0]; zac[dt][1] *= alr[1];
                zac[dt][2] *= alr[2]; zac[dt][3] *= alr[3];
            }
            zacZ[0] *= alr[0]; zacZ[1] *= alr[1];
            zacZ[2] *= alr[2]; zacZ[3] *= alr[3];
            zacE[0] *= alr[0]; zacE[1] *= alr[1];
            zacE[2] *= alr[2]; zacE[3] *= alr[3];
        }

        // masked p and unmasked e -> bf16 LDS frags (no lane reductions)
#pragma unroll
        for (int r = 0; r < 4; ++r) {
            const unsigned w0 = mbr[r * (SEQ / 32) + nt];
            const float e0 = __expf(l0[r] - mx[r]);
            const float e1 = __expf(l1[r] - mx[r]);
            const float p0 = ((w0 >> l15) & 1u)        ? e0 : 0.f;
            const float p1 = ((w0 >> (16 + l15)) & 1u) ? e1 : 0.f;
            const int row = wv * 16 + quad * 4 + r;
            pP[row * 40 + l15]      = bf16_rtne(p0);
            pP[row * 40 + 16 + l15] = bf16_rtne(p1);
            pE[row * 40 + l15]      = bf16_rtne(e0);
            pE[row * 40 + 16 + l15] = bf16_rtne(e1);
        }

        // row-sums via MFMA with immediate ones B-frag: Zm (masked), Za (raw)
        short8 Pf = *(const short8*)&pP[(wv * 16 + l15) * 40 + quad * 8];
        short8 Ef = *(const short8*)&pE[(wv * 16 + l15) * 40 + quad * 8];
        zacZ = MFMA_BF(Pf, onesf, zacZ);
        zacE = MFMA_BF(Ef, onesf, zacE);

        // z += P @ h : P A-frag (wave-private pP), hTS B-frags (swizzled)
        __builtin_amdgcn_s_setprio(1);
#pragma unroll
        for (int dt = 0; dt < 16; ++dt) {
            const int row = dt * 16 + l15;
            const int p   = quad ^ ((row >> 2) & 3);
            short8 Bf = *(const short8*)&hTS[row * 32 + p * 8];
            zac[dt] = MFMA_BF(Pf, Bf, zac[dt]);
        }
        __builtin_amdgcn_s_setprio(0);

        // barrier: everyone done reading cur; DMA(nt+1) — issued one full
        // iteration ago — drains here with a tile's worth of slack.
        __syncthreads();
        if (nt + 2 < 32) issue_tile(cur, (nt + 2) * 32);
    }

    // epilogue: z_bf16 = z / (Zm + EPS*Za)
#pragma unroll
    for (int r = 0; r < 4; ++r) {
        const int a = aw + quad * 4 + r;
        const float inv = 1.0f / (zacZ[r] + EPS * zacE[r]);
        ushort* zr = zout + (((size_t)b * NH + hh) * AG + a) * D;
#pragma unroll
        for (int dt = 0; dt < 16; ++dt)
            zr[dt * 16 + l15] = bf16_rtne(zac[dt][r] * inv);
    }
}

// ---------------------------------------------------------------------------
// out v18: 64x64 tile + XCD swizzle + z16 A-operand LDS-staged via DMA
// double-buffer (proven +9 us vs global-operand MFMA at 2 waves/SIMD).
// ---------------------------------------------------------------------------
__global__ __launch_bounds__(256) void out_mfma(
    const ushort* __restrict__ z16, const ushort* __restrict__ WVt,
    float* __restrict__ out)
{
    __shared__ __align__(16) char olds[65536];
    const int t    = threadIdx.x;
    const int wv   = t >> 6;
    const int lane = t & 63;
    const int l15  = lane & 15;
    const int quad = lane >> 4;
    const int f    = blockIdx.x;               // 512 blocks
    const int b    = (f & 7) + 8 * (f >> 7);   // same-b -> same XCD
    const int mid  = (f >> 3) & 15;
    const int e0   = (mid & 3) * 64;
    const int a0   = (mid >> 2) * 64;
    const int aw   = a0 + wv * 16;

    const ushort* zb = z16 + (size_t)b * NH * AG * D;

    // DMA head-hh tile (rows a0..a0+63, all 256 d) into buf, XOR-swizzled:
    // LDS slot (row, p) holds global col-group c = p ^ (row & 7).
    auto stage = [&](char* buf, int hh) {
        ushort* dst = (ushort*)buf;
        const ushort* src = zb + (size_t)hh * AG * D;
#pragma unroll
        for (int i = 0; i < 8; ++i) {
            const int slot = i * 256 + t;        // 0..2047
            const int row  = slot >> 5;          // 0..63
            const int p    = slot & 31;
            const int c    = p ^ (row & 7);
            async16(dst + (size_t)slot * 8,
                    src + (size_t)(a0 + row) * D + c * 8);
        }
    };

    floatx4 acc[4];
#pragma unroll
    for (int i = 0; i < 4; ++i) acc[i] = (floatx4){0.f, 0.f, 0.f, 0.f};

    stage(olds, 0);
    __syncthreads();

    for (int hh = 0; hh < 8; ++hh) {
        char* cur = olds + (size_t)(hh & 1) * 32768;
        if (hh + 1 < 8) stage(olds + (size_t)((hh + 1) & 1) * 32768, hh + 1);

        ushort* zt = (ushort*)cur;
        const int lrow = wv * 16 + l15;          // LDS row (local a)
#pragma unroll
        for (int ci = 0; ci < 8; ++ci) {
            const int d0 = ci * 32;
            const int g  = ci * 4 + quad;        // global col-group 0..31
            short8 Af = *(const short8*)&zt[(size_t)lrow * 256 +
                                            (g ^ (lrow & 7)) * 8];
#pragma unroll
            for (int et = 0; et < 4; ++et) {
                short8 Bf = *(const short8*)(WVt +
                    ((size_t)hh * D + e0 + et * 16 + l15) * D + d0 + quad * 8);
                acc[et] = MFMA_BF(Af, Bf, acc[et]);
            }
        }
        // implicit vmcnt(0) completes DMA(hh+1); all waves done reading cur
        __syncthreads();
    }

#pragma unroll
    for (int et = 0; et < 4; ++et)
#pragma unroll
        for (int r = 0; r < 4; ++r)
            out[((size_t)b * AG + aw + quad * 4 + r) * D + e0 + et * 16 + l15] =
                acc[et][r] * 0.125f;
}

// ---------------------------------------------------------------------------
extern "C" void kernel_launch(void* const* d_in, const int* in_sizes, int n_in,
                              void* d_out, int out_size, void* d_ws, size_t ws_size,
                              hipStream_t stream)
{
    (void)in_sizes; (void)n_in; (void)out_size; (void)ws_size;
    const float* x     = (const float*)d_in[0];
    const float* m     = (const float*)d_in[1];
    const float* W_enc = (const float*)d_in[2];
    const float* b_enc = (const float*)d_in[3];
    const float* WQ    = (const float*)d_in[4];
    const float* WK    = (const float*)d_in[5];
    const float* WV    = (const float*)d_in[6];
    float* out = (float*)d_out;
    char* ws = (char*)d_ws;

    ushort*   h_hi  = (ushort*)(ws + HHI_OFF);
    ushort*   h_lo  = (ushort*)(ws + HLO_OFF);
    ushort*   hT    = (ushort*)(ws + HT_OFF);
    ushort*   Mt_hi = (ushort*)(ws + MTHI_OFF);
    ushort*   Mt_lo = (ushort*)(ws + MTLO_OFF);
    unsigned* mbits = (unsigned*)(ws + MB_OFF);
    ushort*   WVt   = (ushort*)(ws + WVT_OFF);
    ushort*   z16   = (ushort*)(ws + Z16_OFF);

    enc_prep<<<dim3(1792, 1, 1), dim3(256), 0, stream>>>(
        x, W_enc, b_enc, h_hi, h_lo, hT,
        m, mbits, WV, WVt, WQ, WK, Mt_hi, Mt_lo);
    attn_mfma<<<dim3(512, 1, 1), dim3(512), 0, stream>>>(
        h_hi, h_lo, hT, Mt_hi, Mt_lo, mbits, z16);
    out_mfma<<<dim3(512, 1, 1), dim3(256), 0, stream>>>(z16, WVt, out);
}

// Round 17
// 490.218 us; speedup vs baseline: 1.6025x; 1.0401x over previous
//
#include <hip/hip_runtime.h>
#include <math.h>

namespace {
constexpr int B_N  = 32;
constexpr int SEQ  = 1024;
constexpr int AG   = 256;
constexpr int D    = 256;
constexpr int NH   = 8;
constexpr float SCALE = 0.0625f;
constexpr float EPS   = 1e-12f;

// workspace byte offsets (total ~88 MB)
constexpr size_t HHI_OFF  = 0;          // ushort(bf16) B*SEQ*D = 16 MB
constexpr size_t HLO_OFF  = 16777216;   // ushort(bf16) B*SEQ*D = 16 MB
constexpr size_t HT_OFF   = 33554432;   // ushort(bf16) B*D*SEQ = 16 MB
constexpr size_t MTHI_OFF = 50331648;   // ushort NH*D*D = 1 MB
constexpr size_t MTLO_OFF = 51380224;   // ushort NH*D*D = 1 MB
constexpr size_t MB_OFF   = 52428800;   // u32 B*AG*SEQ/32 = 1 MB
constexpr size_t WVT_OFF  = 53477376;   // ushort NH*D*D = 1 MB
constexpr size_t Z16_OFF  = 54525952;   // ushort B*NH*AG*D = 33.5 MB
}

typedef __attribute__((ext_vector_type(8))) short short8;
typedef __attribute__((ext_vector_type(4))) float floatx4;
#define MFMA_BF(A,B,C) __builtin_amdgcn_mfma_f32_16x16x32_bf16(A,B,C,0,0,0)

__device__ __forceinline__ unsigned short bf16_rtne(float f) {
    unsigned u = __float_as_uint(f);
    u += 0x7fffu + ((u >> 16) & 1u);
    return (unsigned short)(u >> 16);
}
__device__ __forceinline__ float bf16_tof(unsigned short h) {
    return __uint_as_float(((unsigned)h) << 16);
}
// async global->LDS DMA, 16 B/lane; LDS dst = wave-uniform base + lane*16
__device__ __forceinline__ void async16(void* lds, const void* g) {
    __builtin_amdgcn_global_load_lds(
        (const __attribute__((address_space(1))) unsigned int*)g,
        (__attribute__((address_space(3))) unsigned int*)lds,
        16, 0, 0);
}

// ---------------------------------------------------------------------------
// enc_prep v23 (= v22 with mprep staging bug fixed): encoder 128 rows/block
// (v<256): W_enc loaded+converted per block, so halving block count halves
// W traffic (128->64 MB) and W conversions; x still read/converted once.
//   v <  768 : maskbits (1 u32/thread)
//   v <  896 : wvt   (256-thread body, t<256-gated, barriers outside)
//   else     : mprep (v22 BUG: rr=t>>3 is 0..63 so the else/B-branch never
//              ran and WQ was never staged -> absmax 21.9. FIX: each thread
//              owns (rr,k4)=(t>>3, t&7) and loads BOTH A(WK) and B(WQ),
//              original dual-load semantics in one 512-thread pass.)
// ---------------------------------------------------------------------------
__global__ __launch_bounds__(512) void enc_prep(
    const float* __restrict__ x, const float* __restrict__ W_enc,
    const float* __restrict__ b_enc,
    ushort* __restrict__ h_hi, ushort* __restrict__ h_lo,
    ushort* __restrict__ hT,
    const float* __restrict__ m, unsigned* __restrict__ mb,
    const float* __restrict__ WV, ushort* __restrict__ WVt,
    const float* __restrict__ WQ, const float* __restrict__ WK,
    ushort* __restrict__ Mt_hi, ushort* __restrict__ Mt_lo)
{
    __shared__ __align__(16) char slds[61440];
    const int t = threadIdx.x;
    const int v = blockIdx.x;

    if (v < 256) {
        // ---- encoder: h = lrelu(x)@W_enc^T + b (split-bf16 x3 MFMA) + hT
        ushort (*Axh)[40] = (ushort(*)[40])(slds);            // 10240 B
        ushort (*Axl)[40] = (ushort(*)[40])(slds + 10240);    // 10240 B
        ushort (*Bwh)[40] = (ushort(*)[40])(slds + 20480);    // 20480 B
        ushort (*Bwl)[40] = (ushort(*)[40])(slds + 40960);    // 20480 B

        const int wv   = t >> 6;            // 0..7
        const int lane = t & 63;
        const int l15  = lane & 15;
        const int quad = lane >> 4;
        const int row0 = v * 128;

        floatx4 acc[16];
#pragma unroll
        for (int i = 0; i < 16; ++i) acc[i] = (floatx4){0.f, 0.f, 0.f, 0.f};

        for (int k0 = 0; k0 < 256; k0 += 32) {
            __syncthreads();
            {
                // x tile: 128 rows x 32 k; thread: row t>>2, 8 floats
                const int r = t >> 2, s = (t & 3) * 8;
                float f[8];
                *(float4*)&f[0] = *(const float4*)(x + (size_t)(row0 + r) * 256 + k0 + s);
                *(float4*)&f[4] = *(const float4*)(x + (size_t)(row0 + r) * 256 + k0 + s + 4);
                short8 hi8, lo8;
#pragma unroll
                for (int e = 0; e < 8; ++e) {
                    float vv = f[e] > 0.f ? f[e] : 0.01f * f[e];
                    unsigned short hb = bf16_rtne(vv);
                    hi8[e] = (short)hb;
                    lo8[e] = (short)bf16_rtne(vv - bf16_tof(hb));
                }
                *(short8*)&Axh[r][s] = hi8;
                *(short8*)&Axl[r][s] = lo8;
                // W tile: 256 rows x 32 k; thread: row t>>1, 2 chunks of 8
                const int wr = t >> 1, wsb = (t & 1) * 16;
#pragma unroll
                for (int ch = 0; ch < 2; ++ch) {
                    const int ws = wsb + ch * 8;
                    *(float4*)&f[0] = *(const float4*)(W_enc + (size_t)wr * 256 + k0 + ws);
                    *(float4*)&f[4] = *(const float4*)(W_enc + (size_t)wr * 256 + k0 + ws + 4);
#pragma unroll
                    for (int e = 0; e < 8; ++e) {
                        unsigned short hb = bf16_rtne(f[e]);
                        hi8[e] = (short)hb;
                        lo8[e] = (short)bf16_rtne(f[e] - bf16_tof(hb));
                    }
                    *(short8*)&Bwh[wr][ws] = hi8;
                    *(short8*)&Bwl[wr][ws] = lo8;
                }
            }
            __syncthreads();

            short8 Af  = *(const short8*)&Axh[wv * 16 + l15][quad * 8];
            short8 Afl = *(const short8*)&Axl[wv * 16 + l15][quad * 8];
#pragma unroll
            for (int ot = 0; ot < 16; ++ot) {
                short8 Bf  = *(const short8*)&Bwh[ot * 16 + l15][quad * 8];
                short8 Bfl = *(const short8*)&Bwl[ot * 16 + l15][quad * 8];
                acc[ot] = MFMA_BF(Af,  Bf,  acc[ot]);
                acc[ot] = MFMA_BF(Afl, Bf,  acc[ot]);
                acc[ot] = MFMA_BF(Af,  Bfl, acc[ot]);
            }
        }

        // epilogue: 4 col-panels of 64 through reused LDS staging
        ushort (*Th)[72] = (ushort(*)[72])(slds);             // 18432 B
        ushort (*Tl)[72] = (ushort(*)[72])(slds + 18432);     // 18432 B
        const int bq = v >> 3;             // batch
        const int n0 = (v & 7) * 128;      // n-offset within batch
        for (int cp = 0; cp < 4; ++cp) {
            __syncthreads();   // LDS free (k-loop or previous panel done)
#pragma unroll
            for (int et = 0; et < 4; ++et) {
                const int col = et * 16 + l15;
                const float bb = b_enc[cp * 64 + col];
#pragma unroll
                for (int r = 0; r < 4; ++r) {
                    const int row = wv * 16 + quad * 4 + r;
                    const float vv = acc[cp * 4 + et][r] + bb;
                    const unsigned short hb = bf16_rtne(vv);
                    Th[row][col] = hb;
                    Tl[row][col] = bf16_rtne(vv - bf16_tof(hb));
                }
            }
            __syncthreads();
            {
                const int r = t >> 2, c0 = (t & 3) * 16;
                ushort* dh = h_hi + (size_t)(row0 + r) * 256 + cp * 64 + c0;
                ushort* dl = h_lo + (size_t)(row0 + r) * 256 + cp * 64 + c0;
                *(short8*)dh       = *(const short8*)&Th[r][c0];
                *(short8*)(dh + 8) = *(const short8*)&Th[r][c0 + 8];
                *(short8*)dl       = *(const short8*)&Tl[r][c0];
                *(short8*)(dl + 8) = *(const short8*)&Tl[r][c0 + 8];
            }
            {
                const int dd = t >> 3, seg = (t & 7) * 16;
                ushort tmp[16];
#pragma unroll
                for (int j = 0; j < 16; ++j) tmp[j] = Th[seg + j][dd];
                ushort* dst = hT + ((size_t)(bq * 256 + cp * 64 + dd)) * 1024 + n0 + seg;
                *(short8*)dst       = *(short8*)&tmp[0];
                *(short8*)(dst + 8) = *(short8*)&tmp[8];
            }
        }
    } else if (v < 768) {
        // ---- maskbits: 1 u32 per thread
        const int idx = (v - 256) * 512 + t;
        const float4* src = (const float4*)(m + (size_t)idx * 32);
        unsigned wbits = 0;
#pragma unroll
        for (int i = 0; i < 8; ++i) {
            float4 vv = src[i];
            wbits |= (vv.x > 0.5f ? 1u : 0u) << (i * 4 + 0);
            wbits |= (vv.y > 0.5f ? 1u : 0u) << (i * 4 + 1);
            wbits |= (vv.z > 0.5f ? 1u : 0u) << (i * 4 + 2);
            wbits |= (vv.w > 0.5f ? 1u : 0u) << (i * 4 + 3);
        }
        mb[idx] = wbits;
    } else if (v < 896) {
        // ---- wvt: WVt[h][e][d] = bf16(WV[h][d][e]); pitch 68 f32
        float (*T)[68] = (float(*)[68])slds;     // 17408 B
        const int v2 = v - 768;
        const int d0 = (v2 & 3) * 64, e0 = ((v2 >> 2) & 3) * 64, h = v2 >> 4;
        if (t < 256) {
            const int r = t >> 2, c = (t & 3) * 16;
            const float* src = WV + ((size_t)(h * 256 + d0 + r)) * 256 + e0 + c;
#pragma unroll
            for (int j = 0; j < 4; ++j)
                *(float4*)&T[r][c + j * 4] = *(const float4*)(src + j * 4);
        }
        __syncthreads();
        if (t < 256) {
            const int ee = t >> 2, seg = (t & 3) * 16;
            ushort tmp[16];
#pragma unroll
            for (int j = 0; j < 16; ++j) tmp[j] = bf16_rtne(T[seg + j][ee]);
            ushort* dst = WVt + ((size_t)(h * 256 + e0 + ee)) * 256 + d0 + seg;
            *(short8*)dst       = *(short8*)&tmp[0];
            *(short8*)(dst + 8) = *(short8*)&tmp[8];
        }
    } else {
        // ---- mprep: Mt_h[d'][d] = (WQ_h @ WK_h^T)[d][d'] -> bf16 hi/lo
        float (*AsT)[68] = (float(*)[68])slds;           // 8704 B
        float (*BsT)[68] = (float(*)[68])(slds + 8704);  // 8704 B
        const int v3 = v - 896;
        const int tx = t & 15, ty = (t >> 4) & 15;
        const int col0 = (v3 & 3) * 64;
        const int row0 = ((v3 >> 2) & 3) * 64;
        const int hz   = v3 >> 4;
        const float* A  = WK + (size_t)hz * 256 * 256;
        const float* Bm = WQ + (size_t)hz * 256 * 256;
        ushort* Chi = Mt_hi + (size_t)hz * 256 * 256;
        ushort* Clo = Mt_lo + (size_t)hz * 256 * 256;

        float acc[4][4];
#pragma unroll
        for (int r = 0; r < 4; ++r)
#pragma unroll
            for (int c = 0; c < 4; ++c) acc[r][c] = 0.f;

        for (int k0 = 0; k0 < 256; k0 += 32) {
            __syncthreads();
            {
                // FIX: thread owns (rr,k4); loads BOTH A(WK) and B(WQ)
                const int rr = t >> 3, k4 = t & 7;   // 512 thr = 64x8 chunks
                float4 vv = *(const float4*)(A + (size_t)(row0 + rr) * 256 + k0 + k4 * 4);
                AsT[k4*4+0][rr] = vv.x; AsT[k4*4+1][rr] = vv.y;
                AsT[k4*4+2][rr] = vv.z; AsT[k4*4+3][rr] = vv.w;
                float4 wvv = *(const float4*)(Bm + (size_t)(col0 + rr) * 256 + k0 + k4 * 4);
                BsT[k4*4+0][rr] = wvv.x; BsT[k4*4+1][rr] = wvv.y;
                BsT[k4*4+2][rr] = wvv.z; BsT[k4*4+3][rr] = wvv.w;
            }
            __syncthreads();
            if (t < 256) {
#pragma unroll 8
                for (int kk = 0; kk < 32; ++kk) {
                    float4 a4 = *(const float4*)&AsT[kk][ty * 4];
                    float4 b4 = *(const float4*)&BsT[kk][tx * 4];
                    const float ar[4] = {a4.x, a4.y, a4.z, a4.w};
                    const float bc[4] = {b4.x, b4.y, b4.z, b4.w};
#pragma unroll
                    for (int r = 0; r < 4; ++r)
#pragma unroll
                        for (int c = 0; c < 4; ++c)
                            acc[r][c] = fmaf(ar[r], bc[c], acc[r][c]);
                }
            }
        }
        if (t < 256) {
#pragma unroll
            for (int r = 0; r < 4; ++r) {
                const int row = row0 + ty * 4 + r;
                ushort hi4[4], lo4[4];
#pragma unroll
                for (int c = 0; c < 4; ++c) {
                    float vv = acc[r][c];
                    hi4[c] = bf16_rtne(vv);
                    lo4[c] = bf16_rtne(vv - bf16_tof(hi4[c]));
                }
                *(ushort4*)(Chi + (size_t)row * 256 + col0 + tx * 4) =
                    make_ushort4(hi4[0], hi4[1], hi4[2], hi4[3]);
                *(ushort4*)(Clo + (size_t)row * 256 + col0 + tx * 4) =
                    make_ushort4(lo4[0], lo4[1], lo4[2], lo4[3]);
            }
        }
    }
}

// ---------------------------------------------------------------------------
// Attention (proven 330-345 us across runs): v10 structure + neutral setprio.
// Register-pinned at 2 waves/SIMD; MFMA operands must come from LDS
// (v14/v19 measured).
// ---------------------------------------------------------------------------
__global__ __launch_bounds__(512, 2) void attn_mfma(
    const ushort* __restrict__ h_hi, const ushort* __restrict__ h_lo,
    const ushort* __restrict__ hT,   const ushort* __restrict__ Mt_hi,
    const ushort* __restrict__ Mt_lo, const unsigned* __restrict__ mbits,
    ushort* __restrict__ zout)
{
    // buf k at k*49152: hS_hi 16384 | hS_lo 16384 | hTS 16384 ;
    // pP at 98304 (10240) ; pE at 108544 (10240)  -> 118784 B total
    __shared__ __align__(16) char lds[118784];
    ushort* pP = (ushort*)(lds + 98304);   // [128][40] bf16 masked p
    ushort* pE = (ushort*)(lds + 108544);  // [128][40] bf16 unmasked e

    const int t    = threadIdx.x;
    const int wv   = t >> 6;          // 0..7
    const int lane = t & 63;
    const int l15  = lane & 15;
    const int quad = lane >> 4;
    const int f    = blockIdx.x;      // 512 blocks
    const int b    = (f & 7) + 8 * (f >> 7);
    const int mid  = (f >> 3) & 15;
    const int hh   = (mid >> 2) * 2 + (wv >> 2);   // head per wave
    const int a0   = (mid & 3) * 64;
    const int aw   = a0 + (wv & 3) * 16;           // a-subtile per wave

    const ushort* hbh = h_hi + (size_t)b * SEQ * D;
    const ushort* hbl = h_lo + (size_t)b * SEQ * D;
    const ushort* hTb = hT   + (size_t)b * D * SEQ;

    // ---- Phase 0: Q' = ha @ Mt^T (split-bf16 x3), C-layout fp32 tiles
    floatx4 qac[16];
#pragma unroll
    for (int i = 0; i < 16; ++i) qac[i] = (floatx4){0.f, 0.f, 0.f, 0.f};

    for (int kc = 0; kc < 4; ++kc) {
        short8 Ah[2], Al[2];
#pragma unroll
        for (int kt = 0; kt < 2; ++kt) {
            const size_t ao = ((size_t)b * SEQ + aw + l15) * D +
                              kc * 64 + kt * 32 + quad * 8;
            Ah[kt] = *(const short8*)(h_hi + ao);
            Al[kt] = *(const short8*)(h_lo + ao);
        }
#pragma unroll
        for (int nt2 = 0; nt2 < 16; ++nt2) {
#pragma unroll
            for (int kt = 0; kt < 2; ++kt) {
                const size_t mo = ((size_t)hh * D + nt2 * 16 + l15) * D +
                                  kc * 64 + kt * 32 + quad * 8;
                short8 Bh = *(const short8*)(Mt_hi + mo);
                short8 Bl = *(const short8*)(Mt_lo + mo);
                qac[nt2] = MFMA_BF(Ah[kt], Bh, qac[nt2]);
                qac[nt2] = MFMA_BF(Al[kt], Bh, qac[nt2]);
                qac[nt2] = MFMA_BF(Ah[kt], Bl, qac[nt2]);
            }
        }
    }

    // repack Q' C-layout -> bf16 hi/lo A-frags via fp32 scratch in buf0
    // (wave-private rows, pitch 68 f32; 34.8 KB < 49 KB buf0)
    short8 Qhi[8], Qlo[8];
    {
        float* qscr = (float*)lds;
        for (int c = 0; c < 4; ++c) {
#pragma unroll
            for (int j = 0; j < 4; ++j)
#pragma unroll
                for (int r = 0; r < 4; ++r)
                    qscr[(wv * 16 + quad * 4 + r) * 68 + j * 16 + l15] = qac[c * 4 + j][r];
#pragma unroll
            for (int kt = 0; kt < 2; ++kt) {
                const float* pr = &qscr[(wv * 16 + l15) * 68 + kt * 32 + quad * 8];
                float ftmp[8];
                *(float4*)&ftmp[0] = *(const float4*)pr;
                *(float4*)&ftmp[4] = *(const float4*)(pr + 4);
                short8 hi, lo;
#pragma unroll
                for (int e = 0; e < 8; ++e) {
                    unsigned short hb = bf16_rtne(ftmp[e]);
                    hi[e] = (short)hb;
                    lo[e] = (short)bf16_rtne(ftmp[e] - bf16_tof(hb));
                }
                Qhi[c * 2 + kt] = hi;
                Qlo[c * 2 + kt] = lo;
            }
        }
    }
    __syncthreads();   // all waves done with Q' scratch before DMA into buf0

    // ---- DMA issue helper (tile n0 -> buf)
    auto issue_tile = [&](char* buf, int n0) {
        ushort* dh = (ushort*)buf;
        ushort* dl = (ushort*)(buf + 16384);
        ushort* dT = (ushort*)(buf + 32768);
#pragma unroll
        for (int i = 0; i < 2; ++i) {
            const int slot = wv * 128 + i * 64 + lane;
            const int row  = slot >> 5;
            const int p    = slot & 31;
            const int c    = p ^ (row & 7);
            const size_t go = (size_t)(n0 + row) * 256 + c * 8;
            const size_t lo_ = (size_t)(wv * 128 + i * 64) * 8;
            async16(dh + lo_, hbh + go);
            async16(dl + lo_, hbl + go);
        }
#pragma unroll
        for (int i = 0; i < 2; ++i) {
            const int slot = wv * 128 + i * 64 + lane;
            const int row  = slot >> 2;
            const int p    = slot & 3;
            const int c    = p ^ ((row >> 2) & 3);
            async16(dT + (size_t)(wv * 128 + i * 64) * 8,
                    hTb + (size_t)row * 1024 + n0 + c * 8);
        }
    };

    // prologue: tiles 0 and 1 in flight, then drain once
    issue_tile(lds,         0);
    issue_tile(lds + 49152, 32);
    __syncthreads();

    // ---- Phase 1: pipelined flash loop over 32 n-tiles of 32 rows
    floatx4 zac[16];
#pragma unroll
    for (int i = 0; i < 16; ++i) zac[i] = (floatx4){0.f, 0.f, 0.f, 0.f};
    floatx4 zacZ = (floatx4){0.f, 0.f, 0.f, 0.f};   // Zm row-sums (MFMA ones)
    floatx4 zacE = (floatx4){0.f, 0.f, 0.f, 0.f};   // Za row-sums (MFMA ones)
    float mx[4] = {-INFINITY, -INFINITY, -INFINITY, -INFINITY};

    short8 onesf;
#pragma unroll
    for (int e = 0; e < 8; ++e) onesf[e] = (short)0x3F80;   // bf16 1.0

    const unsigned* mbr = mbits + ((size_t)b * AG + aw + quad * 4) * (SEQ / 32);

    for (int nt = 0; nt < 32; ++nt) {
        char* cur = lds + (size_t)(nt & 1) * 49152;
        ushort* hS_hi = (ushort*)cur;
        ushort* hS_lo = (ushort*)(cur + 16384);
        ushort* hTS   = (ushort*)(cur + 32768);

        // S = Q' @ h^T  (split-bf16 x3; swizzled b128 reads; 4 acc chains)
        floatx4 sacH[2], sacL[2];
        sacH[0] = (floatx4){0.f, 0.f, 0.f, 0.f};
        sacH[1] = (floatx4){0.f, 0.f, 0.f, 0.f};
        sacL[0] = (floatx4){0.f, 0.f, 0.f, 0.f};
        sacL[1] = (floatx4){0.f, 0.f, 0.f, 0.f};
        __builtin_amdgcn_s_setprio(1);
#pragma unroll
        for (int ks = 0; ks < 8; ++ks) {
            const int cg = ks * 4 + quad;
#pragma unroll
            for (int ntile = 0; ntile < 2; ++ntile) {
                const int row = ntile * 16 + l15;
                const int off = row * 256 + (cg ^ (row & 7)) * 8;
                short8 Bh = *(const short8*)&hS_hi[off];
                short8 Bl = *(const short8*)&hS_lo[off];
                sacH[ntile] = MFMA_BF(Qhi[ks], Bh, sacH[ntile]);
                sacL[ntile] = MFMA_BF(Qlo[ks], Bh, sacL[ntile]);
                sacL[ntile] = MFMA_BF(Qhi[ks], Bl, sacL[ntile]);
            }
        }
        __builtin_amdgcn_s_setprio(0);

        // logits for this wave's 16x32 tile (4 rows per lane)
        float l0[4], l1[4];
#pragma unroll
        for (int r = 0; r < 4; ++r) {
            l0[r] = (sacH[0][r] + sacL[0][r]) * SCALE;
            l1[r] = (sacH[1][r] + sacL[1][r]) * SCALE;
        }

        // per-row tile max: 4-deep 16-lane butterfly, 4 independent chains
        float mt[4];
#pragma unroll
        for (int r = 0; r < 4; ++r) mt[r] = fmaxf(l0[r], l1[r]);
#pragma unroll
        for (int off = 1; off < 16; off <<= 1) {
#pragma unroll
            for (int r = 0; r < 4; ++r)
                mt[r] = fmaxf(mt[r], __shfl_xor(mt[r], off));
        }

        // deferred rescale (rare, wave-uniform branch)
        const bool need = (mt[0] > mx[0] + 8.0f) || (mt[1] > mx[1] + 8.0f) ||
                          (mt[2] > mx[2] + 8.0f) || (mt[3] > mx[3] + 8.0f);
        if (__any(need)) {
            float alr[4];
#pragma unroll
            for (int r = 0; r < 4; ++r) {
                const float mxn = fmaxf(mx[r], mt[r]);
                alr[r] = __expf(mx[r] - mxn);
                mx[r] = mxn;
            }
#pragma unroll
            for (int dt = 0; dt < 16; ++dt) {
                zac[dt][0] *= alr[0]; zac[dt][1] *= alr[1];
                zac[dt][2] *= alr[2]; zac[dt][3] *= alr[3];
            }
            zacZ[0] *= alr[0]; zacZ[1] *= alr[1];
            zacZ[2] *= alr[2]; zacZ[3] *= alr[3];
            zacE[0] *= alr[0]; zacE[1] *= alr[1];
            zacE[2] *= alr[2]; zacE[3] *= alr[3];
        }

        // masked p and unmasked e -> bf16 LDS frags (no lane reductions)
#pragma unroll
        for (int r = 0; r < 4; ++r) {
            const unsigned w0 = mbr[r * (SEQ / 32) + nt];
            const float e0 = __expf(l0[r] - mx[r]);
            const float e1 = __expf(l1[r] - mx[r]);
            const float p0 = ((w0 >> l15) & 1u)        ? e0 : 0.f;
            const float p1 = ((w0 >> (16 + l15)) & 1u) ? e1 : 0.f;
            const int row = wv * 16 + quad * 4 + r;
            pP[row * 40 + l15]      = bf16_rtne(p0);
            pP[row * 40 + 16 + l15] = bf16_rtne(p1);
            pE[row * 40 + l15]      = bf16_rtne(e0);
            pE[row * 40 + 16 + l15] = bf16_rtne(e1);
        }

        // row-sums via MFMA with immediate ones B-frag: Zm (masked), Za (raw)
        short8 Pf = *(const short8*)&pP[(wv * 16 + l15) * 40 + quad * 8];
        short8 Ef = *(const short8*)&pE[(wv * 16 + l15) * 40 + quad * 8];
        zacZ = MFMA_BF(Pf, onesf, zacZ);
        zacE = MFMA_BF(Ef, onesf, zacE);

        // z += P @ h : P A-frag (wave-private pP), hTS B-frags (swizzled)
        __builtin_amdgcn_s_setprio(1);
#pragma unroll
        for (int dt = 0; dt < 16; ++dt) {
            const int row = dt * 16 + l15;
            const int p   = quad ^ ((row >> 2) & 3);
            short8 Bf = *(const short8*)&hTS[row * 32 + p * 8];
            zac[dt] = MFMA_BF(Pf, Bf, zac[dt]);
        }
        __builtin_amdgcn_s_setprio(0);

        // barrier: everyone done reading cur; DMA(nt+1) — issued one full
        // iteration ago — drains here with a tile's worth of slack.
        __syncthreads();
        if (nt + 2 < 32) issue_tile(cur, (nt + 2) * 32);
    }

    // epilogue: z_bf16 = z / (Zm + EPS*Za)
#pragma unroll
    for (int r = 0; r < 4; ++r) {
        const int a = aw + quad * 4 + r;
        const float inv = 1.0f / (zacZ[r] + EPS * zacE[r]);
        ushort* zr = zout + (((size_t)b * NH + hh) * AG + a) * D;
#pragma unroll
        for (int dt = 0; dt < 16; ++dt)
            zr[dt * 16 + l15] = bf16_rtne(zac[dt][r] * inv);
    }
}

// ---------------------------------------------------------------------------
// out v18: 64x64 tile + XCD swizzle + z16 A-operand LDS-staged via DMA
// double-buffer (proven +9 us vs global-operand MFMA at 2 waves/SIMD).
// ---------------------------------------------------------------------------
__global__ __launch_bounds__(256) void out_mfma(
    const ushort* __restrict__ z16, const ushort* __restrict__ WVt,
    float* __restrict__ out)
{
    __shared__ __align__(16) char olds[65536];
    const int t    = threadIdx.x;
    const int wv   = t >> 6;
    const int lane = t & 63;
    const int l15  = lane & 15;
    const int quad = lane >> 4;
    const int f    = blockIdx.x;               // 512 blocks
    const int b    = (f & 7) + 8 * (f >> 7);   // same-b -> same XCD
    const int mid  = (f >> 3) & 15;
    const int e0   = (mid & 3) * 64;
    const int a0   = (mid >> 2) * 64;
    const int aw   = a0 + wv * 16;

    const ushort* zb = z16 + (size_t)b * NH * AG * D;

    // DMA head-hh tile (rows a0..a0+63, all 256 d) into buf, XOR-swizzled:
    // LDS slot (row, p) holds global col-group c = p ^ (row & 7).
    auto stage = [&](char* buf, int hh) {
        ushort* dst = (ushort*)buf;
        const ushort* src = zb + (size_t)hh * AG * D;
#pragma unroll
        for (int i = 0; i < 8; ++i) {
            const int slot = i * 256 + t;        // 0..2047
            const int row  = slot >> 5;          // 0..63
            const int p    = slot & 31;
            const int c    = p ^ (row & 7);
            async16(dst + (size_t)slot * 8,
                    src + (size_t)(a0 + row) * D + c * 8);
        }
    };

    floatx4 acc[4];
#pragma unroll
    for (int i = 0; i < 4; ++i) acc[i] = (floatx4){0.f, 0.f, 0.f, 0.f};

    stage(olds, 0);
    __syncthreads();

    for (int hh = 0; hh < 8; ++hh) {
        char* cur = olds + (size_t)(hh & 1) * 32768;
        if (hh + 1 < 8) stage(olds + (size_t)((hh + 1) & 1) * 32768, hh + 1);

        ushort* zt = (ushort*)cur;
        const int lrow = wv * 16 + l15;          // LDS row (local a)
#pragma unroll
        for (int ci = 0; ci < 8; ++ci) {
            const int d0 = ci * 32;
            const int g  = ci * 4 + quad;        // global col-group 0..31
            short8 Af = *(const short8*)&zt[(size_t)lrow * 256 +
                                            (g ^ (lrow & 7)) * 8];
#pragma unroll
            for (int et = 0; et < 4; ++et) {
                short8 Bf = *(const short8*)(WVt +
                    ((size_t)hh * D + e0 + et * 16 + l15) * D + d0 + quad * 8);
                acc[et] = MFMA_BF(Af, Bf, acc[et]);
            }
        }
        // implicit vmcnt(0) completes DMA(hh+1); all waves done reading cur
        __syncthreads();
    }

#pragma unroll
    for (int et = 0; et < 4; ++et)
#pragma unroll
        for (int r = 0; r < 4; ++r)
            out[((size_t)b * AG + aw + quad * 4 + r) * D + e0 + et * 16 + l15] =
                acc[et][r] * 0.125f;
}

// ---------------------------------------------------------------------------
extern "C" void kernel_launch(void* const* d_in, const int* in_sizes, int n_in,
                              void* d_out, int out_size, void* d_ws, size_t ws_size,
                              hipStream_t stream)
{
    (void)in_sizes; (void)n_in; (void)out_size; (void)ws_size;
    const float* x     = (const float*)d_in[0];
    const float* m     = (const float*)d_in[1];
    const float* W_enc = (const float*)d_in[2];
    const float* b_enc = (const float*)d_in[3];
    const float* WQ    = (const float*)d_in[4];
    const float* WK    = (const float*)d_in[5];
    const float* WV    = (const float*)d_in[6];
    float* out = (float*)d_out;
    char* ws = (char*)d_ws;

    ushort*   h_hi  = (ushort*)(ws + HHI_OFF);
    ushort*   h_lo  = (ushort*)(ws + HLO_OFF);
    ushort*   hT    = (ushort*)(ws + HT_OFF);
    ushort*   Mt_hi = (ushort*)(ws + MTHI_OFF);
    ushort*   Mt_lo = (ushort*)(ws + MTLO_OFF);
    unsigned* mbits = (unsigned*)(ws + MB_OFF);
    ushort*   WVt   = (ushort*)(ws + WVT_OFF);
    ushort*   z16   = (ushort*)(ws + Z16_OFF);

    enc_prep<<<dim3(1024, 1, 1), dim3(512), 0, stream>>>(
        x, W_enc, b_enc, h_hi, h_lo, hT,
        m, mbits, WV, WVt, WQ, WK, Mt_hi, Mt_lo);
    attn_mfma<<<dim3(512, 1, 1), dim3(512), 0, stream>>>(
        h_hi, h_lo, hT, Mt_hi, Mt_lo, mbits, z16);
    out_mfma<<<dim3(512, 1, 1), dim3(256), 0, stream>>>(z16, WVt, out);
}